// Round 3
// baseline (803.339 us; speedup 1.0000x reference)
//
#include <hip/hip_runtime.h>
#include <stdint.h>

// ---------------------------------------------------------------------------
// Qwen2-7B attention block on gfx950.
// R3: dtype-agnostic. Detect f32-vs-bf16 inputs at runtime, canonicalize to
// an internal bf16 pipeline, store output in detected dtype. GEMM staging via
// registers+ds_write (global_load_lds removed pending green baseline).
// ws layout (peak 48.7 MB):
//   qkvb      [0,        18874368)   bf16 [2048][4608]  (alias: wscr2)
//   attnb     [18874368, 33554432)   bf16 [2048][3584]  (alias: wscr1)
//   hidden_bf [33554432, 48234496)   bf16 [2048][3584]
//   scbf1     [48234496, +258048)    bf16 [28][4608]
//   scbf2     [48492544, +200704)    bf16 [28][3584]
//   biasbf    [48693248, +9216)      bf16 [4608]
//   flag      [48702464, +4)         int  1=bf16 inputs, 0=f32
// ---------------------------------------------------------------------------

typedef short vshort8 __attribute__((ext_vector_type(8)));
typedef __bf16 vbf16x8 __attribute__((ext_vector_type(8)));
typedef float vfloat4 __attribute__((ext_vector_type(4)));

#define SEQ 2048
#define NH 28
#define KVH 4
#define HD 128
#define QSZ 3584
#define QKV_N 4608
#define SM_SCALE 0.08838834764831845f

__device__ __forceinline__ float bf2f(unsigned short h) {
  union { unsigned int u; float f; } x; x.u = ((unsigned int)h) << 16; return x.f;
}
__device__ __forceinline__ unsigned short f2bf(float f) {
  union { unsigned int u; float f; } x; x.f = f;
  x.u += 0x7fff + ((x.u >> 16) & 1);
  return (unsigned short)(x.u >> 16);
}
__device__ __forceinline__ vbf16x8 ld_frag(const unsigned short* p) {
  return __builtin_bit_cast(vbf16x8, *(const vshort8*)p);
}
__device__ __forceinline__ vfloat4 mfma16(vbf16x8 a, vbf16x8 b, vfloat4 c) {
  return __builtin_amdgcn_mfma_f32_16x16x32_bf16(a, b, c, 0, 0, 0);
}

// ---------------------------------------------------------------------------
// Input dtype detection: bf16 tensors have a plausible exponent field in
// every u16; f32 tensors only in odd (high) halves. Count over 2048 u16s.
// ---------------------------------------------------------------------------
__global__ __launch_bounds__(256) void detect_dtype(
    const unsigned short* __restrict__ h, int* __restrict__ flag)
{
  __shared__ int red[256];
  int cnt = 0;
#pragma unroll
  for (int i = 0; i < 8; ++i) {
    unsigned short u = h[threadIdx.x * 8 + i];
    int e = (u >> 7) & 0xFF;
    cnt += (e >= 100 && e <= 150) ? 1 : 0;
  }
  red[threadIdx.x] = cnt;
  __syncthreads();
  for (int s = 128; s > 0; s >>= 1) {
    if (threadIdx.x < s) red[threadIdx.x] += red[threadIdx.x + s];
    __syncthreads();
  }
  if (threadIdx.x == 0) flag[0] = (red[0] >= 1700) ? 1 : 0;
}

// convert f32-or-bf16 -> bf16 (grid*256 == n exactly)
__global__ __launch_bounds__(256) void convert_bf(
    const void* __restrict__ src, unsigned short* __restrict__ dst,
    const int* __restrict__ flag)
{
  int i = blockIdx.x * 256 + threadIdx.x;
  if (flag[0]) dst[i] = ((const unsigned short*)src)[i];
  else         dst[i] = f2bf(((const float*)src)[i]);
}

// ---------------------------------------------------------------------------
// AWQ int4 dequant of an n-chunk -> bf16 transposed weight Wt[n_local][k].
// ---------------------------------------------------------------------------
__global__ __launch_bounds__(256) void dequant_awq(
    const int* __restrict__ qw, const int* __restrict__ qz,
    const unsigned short* __restrict__ scales,  // bf16, row stride NoutStride
    unsigned short* __restrict__ Wt,            // bf16 [CwChunk*8][Kdim]
    int Kdim, int CwChunk, int CwStride, int NoutStride)
{
  int idx = blockIdx.x * 256 + threadIdx.x;   // total = Kdim*CwChunk exactly
  int k = idx % Kdim;
  int c = idx / Kdim;
  int g = k >> 7;                              // group_size = 128
  int w = qw[(size_t)k * CwStride + c];
  int z = qz[(size_t)g * CwStride + c];
#pragma unroll
  for (int j = 0; j < 8; ++j) {
    int wn = (w >> (4 * j)) & 0xF;
    int zn = (z >> (4 * j)) & 0xF;
    float s = bf2f(scales[(size_t)g * NoutStride + c * 8 + j]);
    Wt[(size_t)(c * 8 + j) * Kdim + k] = f2bf((float)(wn - zn) * s);
  }
}

// ---------------------------------------------------------------------------
// bf16 GEMM: C[m][n_base+n] = A[m][K] * Bt[n][K]^T (+bias).
// 128x128 tile, BK=32, 4 waves, 4x4 16x16x32 frags. Register staging.
// Output dtype: bf16 if oflag==nullptr or *oflag==1, else f32.
// ---------------------------------------------------------------------------
__global__ __launch_bounds__(256) void gemm_bt(
    const unsigned short* __restrict__ A,
    const unsigned short* __restrict__ Bt,
    const unsigned short* __restrict__ bias,   // nullable, bf16
    void* __restrict__ Cv, int n_base, int ldc, int K,
    const int* __restrict__ oflag)
{
  __shared__ __align__(16) unsigned short As[128 * 32];
  __shared__ __align__(16) unsigned short Bs[128 * 32];
  const int tid = threadIdx.x;
  const int w = tid >> 6, lane = tid & 63;
  const int c16 = lane & 15, q4 = lane >> 4;
  const int m0 = blockIdx.y * 128, n0 = blockIdx.x * 128;
  const int wr = (w >> 1) * 64, wc = (w & 1) * 64;

  vfloat4 acc[4][4];
#pragma unroll
  for (int i = 0; i < 4; ++i)
#pragma unroll
    for (int j = 0; j < 4; ++j) { vfloat4 z = {0.f, 0.f, 0.f, 0.f}; acc[i][j] = z; }

  const unsigned short* aP0 = A  + (size_t)(m0 + (tid >> 2)) * K + (tid & 3) * 8;
  const unsigned short* aP1 = A  + (size_t)(m0 + 64 + (tid >> 2)) * K + (tid & 3) * 8;
  const unsigned short* bP0 = Bt + (size_t)(n0 + (tid >> 2)) * K + (tid & 3) * 8;
  const unsigned short* bP1 = Bt + (size_t)(n0 + 64 + (tid >> 2)) * K + (tid & 3) * 8;

  for (int k0 = 0; k0 < K; k0 += 32) {
    vshort8 a0 = *(const vshort8*)aP0;
    vshort8 a1 = *(const vshort8*)aP1;
    vshort8 b0 = *(const vshort8*)bP0;
    vshort8 b1 = *(const vshort8*)bP1;
    aP0 += 32; aP1 += 32; bP0 += 32; bP1 += 32;
    __syncthreads();  // prev-iter frag reads complete before overwrite
    *(vshort8*)(As + tid * 8)         = a0;   // chunk c -> halves c*8 (row c/4)
    *(vshort8*)(As + (256 + tid) * 8) = a1;
    *(vshort8*)(Bs + tid * 8)         = b0;
    *(vshort8*)(Bs + (256 + tid) * 8) = b1;
    __syncthreads();
    vbf16x8 af[4], bf[4];
#pragma unroll
    for (int i = 0; i < 4; ++i) af[i] = ld_frag(As + (wr + i * 16 + c16) * 32 + q4 * 8);
#pragma unroll
    for (int j = 0; j < 4; ++j) bf[j] = ld_frag(Bs + (wc + j * 16 + c16) * 32 + q4 * 8);
#pragma unroll
    for (int i = 0; i < 4; ++i)
#pragma unroll
      for (int j = 0; j < 4; ++j)
        acc[i][j] = mfma16(af[i], bf[j], acc[i][j]);
  }

  const int bfm = (oflag == nullptr) ? 1 : oflag[0];
#pragma unroll
  for (int i = 0; i < 4; ++i) {
    int m = m0 + wr + i * 16 + q4 * 4;
#pragma unroll
    for (int j = 0; j < 4; ++j) {
      int n = wc + j * 16 + c16 + n0;
      float bv = bias ? bf2f(bias[n]) : 0.f;
#pragma unroll
      for (int r = 0; r < 4; ++r) {
        float v = acc[i][j][r] + bv;
        size_t idx = (size_t)(m + r) * ldc + n + n_base;
        if (bfm) ((unsigned short*)Cv)[idx] = f2bf(v);
        else     ((float*)Cv)[idx] = v;
      }
    }
  }
}

// ---------------------------------------------------------------------------
// RoPE in place on qkv buffer [SEQ][4608]: q heads (28) + k heads (4).
// ---------------------------------------------------------------------------
__global__ __launch_bounds__(256) void rope_kernel(
    unsigned short* __restrict__ qkv, const int* __restrict__ pos)
{
  int idx = blockIdx.x * 256 + threadIdx.x;  // SEQ*32*64
  int j = idx & 63;
  int h2 = (idx >> 6) & 31;
  int s = idx >> 11;
  unsigned short* row = qkv + (size_t)s * QKV_N;
  int col = (h2 < NH) ? (h2 * HD + j) : (QSZ + (h2 - NH) * HD + j);
  float inv = exp2f(-(float)j * 0.31143079014569017f);  // 1e6^(-j/64)
  float ang = (float)pos[s] * inv;
  float sn, cs;
  sincosf(ang, &sn, &cs);
  float x1 = bf2f(row[col]);
  float x2 = bf2f(row[col + 64]);
  row[col]      = f2bf(x1 * cs - x2 * sn);
  row[col + 64] = f2bf(x2 * cs + x1 * sn);
}

// ---------------------------------------------------------------------------
// GQA causal flash attention. Block = (head, 128-row Q tile), 4 waves x 32 rows.
// ---------------------------------------------------------------------------
__global__ __launch_bounds__(256) void attn_kernel(
    const unsigned short* __restrict__ qkv,  // [SEQ][4608] post-rope
    unsigned short* __restrict__ attn)       // [SEQ][3584]
{
  __shared__ __align__(16) unsigned short kv[9216];        // K:[64][136] / Vt:[128][72]
  __shared__ __align__(16) unsigned short pb[4 * 32 * 72]; // per-wave P
  const int tid = threadIdx.x, w = tid >> 6, lane = tid & 63;
  const int c16 = lane & 15, q4 = lane >> 4;
  const int h = blockIdx.x >> 4;      // 28 heads
  const int qt = blockIdx.x & 15;
  const int q0 = qt * 128;
  const int kvh = h / 7;
  unsigned short* pw = pb + w * 2304;

  vbf16x8 qf[2][4];
#pragma unroll
  for (int i = 0; i < 2; ++i)
#pragma unroll
    for (int kk = 0; kk < 4; ++kk)
      qf[i][kk] = ld_frag(qkv + (size_t)(q0 + w * 32 + i * 16 + c16) * QKV_N
                          + h * HD + kk * 32 + q4 * 8);

  vfloat4 of[2][8];
  float m_run[2][4], l_run[2][4];
#pragma unroll
  for (int i = 0; i < 2; ++i) {
#pragma unroll
    for (int r = 0; r < 4; ++r) { m_run[i][r] = -1e30f; l_run[i][r] = 0.f; }
#pragma unroll
    for (int j = 0; j < 8; ++j) { vfloat4 z = {0.f, 0.f, 0.f, 0.f}; of[i][j] = z; }
  }

  const int n_kt = 2 * (qt + 1);
  for (int kt = 0; kt < n_kt; ++kt) {
    const int k0 = kt * 64;
    __syncthreads();  // prev-iter Vt reads done before K overwrite
#pragma unroll
    for (int it = 0; it < 4; ++it) {
      int chunk = it * 256 + tid;
      int key = chunk >> 4, sub = chunk & 15;
      vshort8 v = *(const vshort8*)(qkv + (size_t)(k0 + key) * QKV_N
                                    + QSZ + kvh * HD + sub * 8);
      *(vshort8*)(kv + key * 136 + sub * 8) = v;
    }
    __syncthreads();

    vfloat4 sf[2][4];
#pragma unroll
    for (int i = 0; i < 2; ++i)
#pragma unroll
      for (int j = 0; j < 4; ++j) { vfloat4 z = {0.f, 0.f, 0.f, 0.f}; sf[i][j] = z; }
#pragma unroll
    for (int j = 0; j < 4; ++j)
#pragma unroll
      for (int kk = 0; kk < 4; ++kk) {
        vbf16x8 b = ld_frag(kv + (j * 16 + c16) * 136 + kk * 32 + q4 * 8);
        sf[0][j] = mfma16(qf[0][kk], b, sf[0][j]);
        sf[1][j] = mfma16(qf[1][kk], b, sf[1][j]);
      }

    float alpha[2][4];
#pragma unroll
    for (int i = 0; i < 2; ++i) {
#pragma unroll
      for (int r = 0; r < 4; ++r) {
        int row = q0 + w * 32 + i * 16 + q4 * 4 + r;
        float mx = -1e30f;
#pragma unroll
        for (int j = 0; j < 4; ++j) {
          int col = k0 + j * 16 + c16;
          float v = sf[i][j][r] * SM_SCALE;
          v = (col > row) ? -1e30f : v;
          sf[i][j][r] = v;
          mx = fmaxf(mx, v);
        }
        mx = fmaxf(mx, __shfl_xor(mx, 1));
        mx = fmaxf(mx, __shfl_xor(mx, 2));
        mx = fmaxf(mx, __shfl_xor(mx, 4));
        mx = fmaxf(mx, __shfl_xor(mx, 8));
        float mn = fmaxf(m_run[i][r], mx);
        float al = __expf(m_run[i][r] - mn);
        m_run[i][r] = mn;
        float rs = 0.f;
#pragma unroll
        for (int j = 0; j < 4; ++j) {
          float e = __expf(sf[i][j][r] - mn);
          sf[i][j][r] = e;
          rs += e;
        }
        rs += __shfl_xor(rs, 1);
        rs += __shfl_xor(rs, 2);
        rs += __shfl_xor(rs, 4);
        rs += __shfl_xor(rs, 8);
        l_run[i][r] = l_run[i][r] * al + rs;
        alpha[i][r] = al;
      }
    }
#pragma unroll
    for (int i = 0; i < 2; ++i)
#pragma unroll
      for (int j = 0; j < 8; ++j)
#pragma unroll
        for (int r = 0; r < 4; ++r)
          of[i][j][r] *= alpha[i][r];
#pragma unroll
    for (int i = 0; i < 2; ++i)
#pragma unroll
      for (int r = 0; r < 4; ++r)
#pragma unroll
        for (int j = 0; j < 4; ++j)
          pw[(i * 16 + q4 * 4 + r) * 72 + j * 16 + c16] = f2bf(sf[i][j][r]);

    __syncthreads();  // all waves done reading K before V overwrite
#pragma unroll
    for (int it = 0; it < 4; ++it) {
      int sub = it * 4 + w;
      vshort8 v = *(const vshort8*)(qkv + (size_t)(k0 + lane) * QKV_N
                                    + QSZ + 512 + kvh * HD + sub * 8);
#pragma unroll
      for (int jj = 0; jj < 8; ++jj)
        kv[(sub * 8 + jj) * 72 + lane] = (unsigned short)v[jj];
    }
    __syncthreads();

#pragma unroll
    for (int kk = 0; kk < 2; ++kk) {
      vbf16x8 a0 = ld_frag(pw + (c16) * 72 + kk * 32 + q4 * 8);
      vbf16x8 a1 = ld_frag(pw + (16 + c16) * 72 + kk * 32 + q4 * 8);
#pragma unroll
      for (int j = 0; j < 8; ++j) {
        vbf16x8 b = ld_frag(kv + (j * 16 + c16) * 72 + kk * 32 + q4 * 8);
        of[0][j] = mfma16(a0, b, of[0][j]);
        of[1][j] = mfma16(a1, b, of[1][j]);
      }
    }
  }

#pragma unroll
  for (int i = 0; i < 2; ++i)
#pragma unroll
    for (int r = 0; r < 4; ++r) {
      int row = q0 + w * 32 + i * 16 + q4 * 4 + r;
      float inv_l = 1.f / l_run[i][r];
#pragma unroll
      for (int j = 0; j < 8; ++j)
        attn[(size_t)row * QSZ + h * HD + j * 16 + c16] = f2bf(of[i][j][r] * inv_l);
    }
}

// ---------------------------------------------------------------------------
extern "C" void kernel_launch(void* const* d_in, const int* in_sizes, int n_in,
                              void* d_out, int out_size, void* d_ws, size_t ws_size,
                              hipStream_t stream)
{
  const void* hidden = d_in[0];                          // f32 or bf16 [2048][3584]
  const int*  pos    = (const int*)d_in[1];              // [2048]
  const int*  qkv_qw = (const int*)d_in[2];              // [3584][576]
  const int*  qkv_qz = (const int*)d_in[3];              // [28][576]
  const void* qkv_sc = d_in[4];                          // [28][4608]
  const void* qkv_bs = d_in[5];                          // [4608]
  const int*  o_qw   = (const int*)d_in[6];              // [3584][448]
  const int*  o_qz   = (const int*)d_in[7];              // [28][448]
  const void* o_sc   = d_in[8];                          // [28][3584]

  char* ws = (char*)d_ws;
  unsigned short* qkvb   = (unsigned short*)ws;               // [2048][4608]
  unsigned short* attnb  = (unsigned short*)(ws + 18874368);  // [2048][3584]
  unsigned short* hidbf  = (unsigned short*)(ws + 33554432);  // [2048][3584]
  unsigned short* scbf1  = (unsigned short*)(ws + 48234496);  // [28][4608]
  unsigned short* scbf2  = (unsigned short*)(ws + 48492544);  // [28][3584]
  unsigned short* biasbf = (unsigned short*)(ws + 48693248);  // [4608]
  int*            flag   = (int*)(ws + 48702464);
  unsigned short* wscr1  = attnb;  // qkv weight chunks [1536][3584]
  unsigned short* wscr2  = qkvb;   // o weight chunks  [1792][3584]

  detect_dtype<<<1, 256, 0, stream>>>((const unsigned short*)hidden, flag);
  convert_bf<<<28672, 256, 0, stream>>>(hidden, hidbf, flag);   // 7340032
  convert_bf<<<504, 256, 0, stream>>>(qkv_sc, scbf1, flag);     // 129024
  convert_bf<<<18, 256, 0, stream>>>(qkv_bs, biasbf, flag);     // 4608
  convert_bf<<<392, 256, 0, stream>>>(o_sc, scbf2, flag);       // 100352

  // QKV: 3 chunks of 1536 output cols (192 word-cols)
  for (int c = 0; c < 3; ++c) {
    dequant_awq<<<2688, 256, 0, stream>>>(
        qkv_qw + c * 192, qkv_qz + c * 192, scbf1 + c * 1536, wscr1,
        3584, 192, 576, 4608);
    gemm_bt<<<dim3(12, 16), 256, 0, stream>>>(
        hidbf, wscr1, biasbf + c * 1536, qkvb, c * 1536, 4608, 3584, nullptr);
  }
  rope_kernel<<<16384, 256, 0, stream>>>(qkvb, pos);
  attn_kernel<<<448, 256, 0, stream>>>(qkvb, attnb);
  // O-proj: 2 chunks of 1792 output cols (224 word-cols)
  for (int c = 0; c < 2; ++c) {
    dequant_awq<<<3136, 256, 0, stream>>>(
        o_qw + c * 224, o_qz + c * 224, scbf2 + c * 1792, wscr2,
        3584, 224, 448, 3584);
    gemm_bt<<<dim3(14, 16), 256, 0, stream>>>(
        attnb, wscr2, nullptr, d_out, c * 1792, 3584, 3584, flag);
  }
}

// Round 4
// 661.254 us; speedup vs baseline: 1.2149x; 1.2149x over previous
//
#include <hip/hip_runtime.h>
#include <stdint.h>

// ---------------------------------------------------------------------------
// Qwen2-7B attention block on gfx950.
// R4: attention split-K + ones-column l-accumulation + 2-barrier iter;
//     GEMM restored to m97 global_load_lds staging with 2-chunk weights.
// ws layout (peak 43.7 MB, known-safe <= 48.7):
//   qkvb   [0, 18874368)            bf16 [2048][4608]   (alias: o-weight scratch)
//   attnb  [18874368, 33554432)     bf16 [2048][3584]
//   wscr1  [18874368, 35389440)     qkv-weight chunks [2304][3584] (dead b4 attn)
//   part1  [35389440, 42729472)     bf16 [224][128][128] chunk-1 partials
//   ml     [42729472, 43188224)     f32  [224][128][4]  (m0,l0,m1,l1)
//   flag   [43188224, +4)
//   scbf1  [43188240, +258048) / scbf2 [43446288, +200704) / biasbf [43646992, +9216)
//   hidden_bf lives in d_out (dead until gemm2 writes it).
// ---------------------------------------------------------------------------

typedef short vshort8 __attribute__((ext_vector_type(8)));
typedef __bf16 vbf16x8 __attribute__((ext_vector_type(8)));
typedef float vfloat4 __attribute__((ext_vector_type(4)));

#define SEQ 2048
#define NH 28
#define KVH 4
#define HD 128
#define QSZ 3584
#define QKV_N 4608
#define SM_SCALE 0.08838834764831845f

__device__ __forceinline__ float bf2f(unsigned short h) {
  union { unsigned int u; float f; } x; x.u = ((unsigned int)h) << 16; return x.f;
}
__device__ __forceinline__ unsigned short f2bf(float f) {
  union { unsigned int u; float f; } x; x.f = f;
  x.u += 0x7fff + ((x.u >> 16) & 1);
  return (unsigned short)(x.u >> 16);
}
__device__ __forceinline__ vbf16x8 ld_frag(const unsigned short* p) {
  return __builtin_bit_cast(vbf16x8, *(const vshort8*)p);
}
__device__ __forceinline__ vfloat4 mfma16(vbf16x8 a, vbf16x8 b, vfloat4 c) {
  return __builtin_amdgcn_mfma_f32_16x16x32_bf16(a, b, c, 0, 0, 0);
}
__device__ __forceinline__ void async_cp16(const unsigned short* g, unsigned short* l) {
  __builtin_amdgcn_global_load_lds((const __attribute__((address_space(1))) void*)g,
                                   (__attribute__((address_space(3))) void*)l, 16, 0, 0);
}

// ---------------------------------------------------------------------------
__global__ __launch_bounds__(256) void detect_dtype(
    const unsigned short* __restrict__ h, int* __restrict__ flag)
{
  __shared__ int red[256];
  int cnt = 0;
#pragma unroll
  for (int i = 0; i < 8; ++i) {
    unsigned short u = h[threadIdx.x * 8 + i];
    int e = (u >> 7) & 0xFF;
    cnt += (e >= 100 && e <= 150) ? 1 : 0;
  }
  red[threadIdx.x] = cnt;
  __syncthreads();
  for (int s = 128; s > 0; s >>= 1) {
    if (threadIdx.x < s) red[threadIdx.x] += red[threadIdx.x + s];
    __syncthreads();
  }
  if (threadIdx.x == 0) flag[0] = (red[0] >= 1700) ? 1 : 0;
}

__global__ __launch_bounds__(256) void convert_bf(
    const void* __restrict__ src, unsigned short* __restrict__ dst,
    const int* __restrict__ flag)
{
  int i = blockIdx.x * 256 + threadIdx.x;
  if (flag[0]) dst[i] = ((const unsigned short*)src)[i];
  else         dst[i] = f2bf(((const float*)src)[i]);
}

// ---------------------------------------------------------------------------
// AWQ int4 dequant of an n-chunk -> bf16 transposed weight Wt[n_local][k].
// ---------------------------------------------------------------------------
__global__ __launch_bounds__(256) void dequant_awq(
    const int* __restrict__ qw, const int* __restrict__ qz,
    const unsigned short* __restrict__ scales,
    unsigned short* __restrict__ Wt,
    int Kdim, int CwChunk, int CwStride, int NoutStride)
{
  int idx = blockIdx.x * 256 + threadIdx.x;
  int k = idx % Kdim;
  int c = idx / Kdim;
  int g = k >> 7;
  int w = qw[(size_t)k * CwStride + c];
  int z = qz[(size_t)g * CwStride + c];
#pragma unroll
  for (int j = 0; j < 8; ++j) {
    int wn = (w >> (4 * j)) & 0xF;
    int zn = (z >> (4 * j)) & 0xF;
    float s = bf2f(scales[(size_t)g * NoutStride + c * 8 + j]);
    Wt[(size_t)(c * 8 + j) * Kdim + k] = f2bf((float)(wn - zn) * s);
  }
}

// ---------------------------------------------------------------------------
// m97-style bf16 GEMM with global_load_lds width-16 staging.
// ---------------------------------------------------------------------------
__global__ __launch_bounds__(256) void gemm_bt(
    const unsigned short* __restrict__ A,
    const unsigned short* __restrict__ Bt,
    const unsigned short* __restrict__ bias,
    void* __restrict__ Cv, int n_base, int ldc, int K,
    const int* __restrict__ oflag)
{
  __shared__ __align__(16) unsigned short As[128 * 32];
  __shared__ __align__(16) unsigned short Bs[128 * 32];
  const int tid = threadIdx.x;
  const int w = tid >> 6, lane = tid & 63;
  const int c16 = lane & 15, q4 = lane >> 4;
  const int m0 = blockIdx.y * 128, n0 = blockIdx.x * 128;
  const int wr = (w >> 1) * 64, wc = (w & 1) * 64;

  vfloat4 acc[4][4];
#pragma unroll
  for (int i = 0; i < 4; ++i)
#pragma unroll
    for (int j = 0; j < 4; ++j) { vfloat4 z = {0.f, 0.f, 0.f, 0.f}; acc[i][j] = z; }

  const unsigned short* aP0 = A  + (size_t)(m0 + (tid >> 2)) * K + (tid & 3) * 8;
  const unsigned short* aP1 = A  + (size_t)(m0 + 64 + (tid >> 2)) * K + (tid & 3) * 8;
  const unsigned short* bP0 = Bt + (size_t)(n0 + (tid >> 2)) * K + (tid & 3) * 8;
  const unsigned short* bP1 = Bt + (size_t)(n0 + 64 + (tid >> 2)) * K + (tid & 3) * 8;
  unsigned short* lA0 = As + (w * 64) * 8;
  unsigned short* lA1 = As + (256 + w * 64) * 8;
  unsigned short* lB0 = Bs + (w * 64) * 8;
  unsigned short* lB1 = Bs + (256 + w * 64) * 8;

  for (int k0 = 0; k0 < K; k0 += 32) {
    async_cp16(aP0, lA0);
    async_cp16(aP1, lA1);
    async_cp16(bP0, lB0);
    async_cp16(bP1, lB1);
    aP0 += 32; aP1 += 32; bP0 += 32; bP1 += 32;
    __builtin_amdgcn_s_waitcnt(0);
    __syncthreads();
    vbf16x8 af[4], bf[4];
#pragma unroll
    for (int i = 0; i < 4; ++i) af[i] = ld_frag(As + (wr + i * 16 + c16) * 32 + q4 * 8);
#pragma unroll
    for (int j = 0; j < 4; ++j) bf[j] = ld_frag(Bs + (wc + j * 16 + c16) * 32 + q4 * 8);
#pragma unroll
    for (int i = 0; i < 4; ++i)
#pragma unroll
      for (int j = 0; j < 4; ++j)
        acc[i][j] = mfma16(af[i], bf[j], acc[i][j]);
    __syncthreads();
  }

  const int bfm = (oflag == nullptr) ? 1 : oflag[0];
#pragma unroll
  for (int i = 0; i < 4; ++i) {
    int m = m0 + wr + i * 16 + q4 * 4;
#pragma unroll
    for (int j = 0; j < 4; ++j) {
      int n = wc + j * 16 + c16 + n0;
      float bv = bias ? bf2f(bias[n]) : 0.f;
#pragma unroll
      for (int r = 0; r < 4; ++r) {
        float v = acc[i][j][r] + bv;
        size_t idx = (size_t)(m + r) * ldc + n + n_base;
        if (bfm) ((unsigned short*)Cv)[idx] = f2bf(v);
        else     ((float*)Cv)[idx] = v;
      }
    }
  }
}

// ---------------------------------------------------------------------------
__global__ __launch_bounds__(256) void rope_kernel(
    unsigned short* __restrict__ qkv, const int* __restrict__ pos)
{
  int idx = blockIdx.x * 256 + threadIdx.x;
  int j = idx & 63;
  int h2 = (idx >> 6) & 31;
  int s = idx >> 11;
  unsigned short* row = qkv + (size_t)s * QKV_N;
  int col = (h2 < NH) ? (h2 * HD + j) : (QSZ + (h2 - NH) * HD + j);
  float inv = exp2f(-(float)j * 0.31143079014569017f);
  float ang = (float)pos[s] * inv;
  float sn, cs;
  sincosf(ang, &sn, &cs);
  float x1 = bf2f(row[col]);
  float x2 = bf2f(row[col + 64]);
  row[col]      = f2bf(x1 * cs - x2 * sn);
  row[col + 64] = f2bf(x2 * cs + x1 * sn);
}

// ---------------------------------------------------------------------------
// GQA causal flash attention, split-K 2-way for qt>=8.
// Block: (head, 128-row Q-tile, chunk). 4 waves x 32 rows. 64-key K iters.
// l accumulated via all-ones B-tile in the PV MFMA (of[:,8]) — no sum shuffles.
// 2 barriers/iter; K+V staged together at loop top into disjoint LDS.
// ---------------------------------------------------------------------------
__global__ __launch_bounds__(256) void attn_kernel(
    const unsigned short* __restrict__ qkv,   // [SEQ][4608] post-rope
    unsigned short* __restrict__ attnb,       // [SEQ][3584]
    unsigned short* __restrict__ part1,       // [224][128][128] chunk-1 partials
    float* __restrict__ ml)                   // [224][128][4]
{
  __shared__ __align__(16) unsigned short kvK[64 * 136];
  __shared__ __align__(16) unsigned short kvV[128 * 72];
  __shared__ __align__(16) unsigned short pb[4 * 32 * 72];
  const int tid = threadIdx.x, w = tid >> 6, lane = tid & 63;
  const int c16 = lane & 15, q4 = lane >> 4;

  int bid = blockIdx.x;
  int h, qt, chunk, kt0, kt1, t = 0;
  if (bid < 448) {                       // split tiles, longest first
    h = bid >> 4; int s = bid & 15;
    qt = 15 - (s >> 1); chunk = s & 1;
    int half = qt + 1;
    kt0 = chunk * half; kt1 = kt0 + half;
    t = h * 8 + (qt - 8);
  } else {                               // direct tiles qt 7..0
    int d = bid - 448; h = d >> 3; qt = 7 - (d & 7); chunk = -1;
    kt0 = 0; kt1 = 2 * (qt + 1);
  }
  const int q0 = qt * 128;
  const int kvh = h / 7;
  unsigned short* pw = pb + w * 2304;

  vbf16x8 qf[2][4];
#pragma unroll
  for (int i = 0; i < 2; ++i)
#pragma unroll
    for (int kk = 0; kk < 4; ++kk)
      qf[i][kk] = ld_frag(qkv + (size_t)(q0 + w * 32 + i * 16 + c16) * QKV_N
                          + h * HD + kk * 32 + q4 * 8);

  vfloat4 of[2][9];
  float m_run[2][4];
#pragma unroll
  for (int i = 0; i < 2; ++i) {
#pragma unroll
    for (int r = 0; r < 4; ++r) m_run[i][r] = -1e30f;
#pragma unroll
    for (int j = 0; j < 9; ++j) { vfloat4 z = {0.f, 0.f, 0.f, 0.f}; of[i][j] = z; }
  }
  const vshort8 ones_s = {(short)0x3F80, (short)0x3F80, (short)0x3F80, (short)0x3F80,
                          (short)0x3F80, (short)0x3F80, (short)0x3F80, (short)0x3F80};
  const vbf16x8 onesf = __builtin_bit_cast(vbf16x8, ones_s);

  for (int kt = kt0; kt < kt1; ++kt) {
    const int k0 = kt * 64;
    __syncthreads();  // all prior-iter kvK/kvV reads complete
    // stage K [64][136]
#pragma unroll
    for (int it = 0; it < 4; ++it) {
      int cidx = it * 256 + tid;
      int key = cidx >> 4, sub = cidx & 15;
      vshort8 v = *(const vshort8*)(qkv + (size_t)(k0 + key) * QKV_N
                                    + QSZ + kvh * HD + sub * 8);
      *(vshort8*)(kvK + key * 136 + sub * 8) = v;
    }
    // stage V^T [128 d][72 keys]
#pragma unroll
    for (int it = 0; it < 4; ++it) {
      int sub = it * 4 + w;
      vshort8 v = *(const vshort8*)(qkv + (size_t)(k0 + lane) * QKV_N
                                    + QSZ + 512 + kvh * HD + sub * 8);
#pragma unroll
      for (int jj = 0; jj < 8; ++jj)
        kvV[(sub * 8 + jj) * 72 + lane] = (unsigned short)v[jj];
    }
    __syncthreads();

    // S = Q K^T
    vfloat4 sf[2][4];
#pragma unroll
    for (int i = 0; i < 2; ++i)
#pragma unroll
      for (int j = 0; j < 4; ++j) { vfloat4 z = {0.f, 0.f, 0.f, 0.f}; sf[i][j] = z; }
#pragma unroll
    for (int j = 0; j < 4; ++j)
#pragma unroll
      for (int kk = 0; kk < 4; ++kk) {
        vbf16x8 b = ld_frag(kvK + (j * 16 + c16) * 136 + kk * 32 + q4 * 8);
        sf[0][j] = mfma16(qf[0][kk], b, sf[0][j]);
        sf[1][j] = mfma16(qf[1][kk], b, sf[1][j]);
      }

    // scale + mask + online softmax (max only; l via ones-column MFMA)
    float alpha[2][4];
#pragma unroll
    for (int i = 0; i < 2; ++i) {
#pragma unroll
      for (int r = 0; r < 4; ++r) {
        int row = q0 + w * 32 + i * 16 + q4 * 4 + r;
        float mx = -1e30f;
#pragma unroll
        for (int j = 0; j < 4; ++j) {
          int col = k0 + j * 16 + c16;
          float v = sf[i][j][r] * SM_SCALE;
          v = (col > row) ? -1e30f : v;
          sf[i][j][r] = v;
          mx = fmaxf(mx, v);
        }
        mx = fmaxf(mx, __shfl_xor(mx, 1));
        mx = fmaxf(mx, __shfl_xor(mx, 2));
        mx = fmaxf(mx, __shfl_xor(mx, 4));
        mx = fmaxf(mx, __shfl_xor(mx, 8));
        float mn = fmaxf(m_run[i][r], mx);
        alpha[i][r] = __expf(m_run[i][r] - mn);
        m_run[i][r] = mn;
#pragma unroll
        for (int j = 0; j < 4; ++j)
          sf[i][j][r] = __expf(sf[i][j][r] - mn);
      }
    }
#pragma unroll
    for (int i = 0; i < 2; ++i)
#pragma unroll
      for (int j = 0; j < 9; ++j)
#pragma unroll
        for (int r = 0; r < 4; ++r)
          of[i][j][r] *= alpha[i][r];
    // P -> per-wave LDS (same-wave write->read; DS in-order + compiler lgkm)
#pragma unroll
    for (int i = 0; i < 2; ++i)
#pragma unroll
      for (int r = 0; r < 4; ++r)
#pragma unroll
        for (int j = 0; j < 4; ++j)
          pw[(i * 16 + q4 * 4 + r) * 72 + j * 16 + c16] = f2bf(sf[i][j][r]);

    // O += P V  (plus ones-column -> l in of[:,8])
#pragma unroll
    for (int kk = 0; kk < 2; ++kk) {
      vbf16x8 a0 = ld_frag(pw + (c16) * 72 + kk * 32 + q4 * 8);
      vbf16x8 a1 = ld_frag(pw + (16 + c16) * 72 + kk * 32 + q4 * 8);
#pragma unroll
      for (int j = 0; j < 8; ++j) {
        vbf16x8 b = ld_frag(kvV + (j * 16 + c16) * 72 + kk * 32 + q4 * 8);
        of[0][j] = mfma16(a0, b, of[0][j]);
        of[1][j] = mfma16(a1, b, of[1][j]);
      }
      of[0][8] = mfma16(a0, onesf, of[0][8]);
      of[1][8] = mfma16(a1, onesf, of[1][8]);
    }
  }

  // epilogue
#pragma unroll
  for (int i = 0; i < 2; ++i)
#pragma unroll
    for (int r = 0; r < 4; ++r) {
      int lr = w * 32 + i * 16 + q4 * 4 + r;
      int row = q0 + lr;
      float l = of[i][8][r];
      if (chunk < 0) {
        float inv_l = 1.f / l;
#pragma unroll
        for (int j = 0; j < 8; ++j)
          attnb[(size_t)row * QSZ + h * HD + j * 16 + c16] = f2bf(of[i][j][r] * inv_l);
      } else if (chunk == 0) {
#pragma unroll
        for (int j = 0; j < 8; ++j)
          attnb[(size_t)row * QSZ + h * HD + j * 16 + c16] = f2bf(of[i][j][r]);
        if (c16 == 0) { ml[t * 512 + lr * 4 + 0] = m_run[i][r]; ml[t * 512 + lr * 4 + 1] = l; }
      } else {
#pragma unroll
        for (int j = 0; j < 8; ++j)
          part1[(size_t)t * 16384 + lr * 128 + j * 16 + c16] = f2bf(of[i][j][r]);
        if (c16 == 0) { ml[t * 512 + lr * 4 + 2] = m_run[i][r]; ml[t * 512 + lr * 4 + 3] = l; }
      }
    }
}

// ---------------------------------------------------------------------------
// Merge the two split-K partials for qt>=8 tiles.
// ---------------------------------------------------------------------------
__global__ __launch_bounds__(256) void combine_kernel(
    unsigned short* __restrict__ attnb, const unsigned short* __restrict__ part1,
    const float* __restrict__ ml)
{
  int t = blockIdx.x;
  int h = t >> 3, qt = (t & 7) + 8;
  int lr = threadIdx.x >> 1, ch = (threadIdx.x & 1) * 64;
  int row = qt * 128 + lr;
  float m0 = ml[t * 512 + lr * 4 + 0], l0 = ml[t * 512 + lr * 4 + 1];
  float m1 = ml[t * 512 + lr * 4 + 2], l1 = ml[t * 512 + lr * 4 + 3];
  float M = fmaxf(m0, m1);
  float w0 = __expf(m0 - M), w1 = __expf(m1 - M);
  float inv = 1.f / (l0 * w0 + l1 * w1);
  unsigned short* dst = attnb + (size_t)row * QSZ + h * HD + ch;
  const unsigned short* src = part1 + (size_t)t * 16384 + lr * 128 + ch;
#pragma unroll
  for (int k = 0; k < 8; ++k) {
    vshort8 a = *(const vshort8*)(dst + k * 8);
    vshort8 b = *(const vshort8*)(src + k * 8);
    vshort8 o;
#pragma unroll
    for (int jj = 0; jj < 8; ++jj)
      o[jj] = (short)f2bf((bf2f((unsigned short)a[jj]) * w0 +
                           bf2f((unsigned short)b[jj]) * w1) * inv);
    *(vshort8*)(dst + k * 8) = o;
  }
}

// ---------------------------------------------------------------------------
extern "C" void kernel_launch(void* const* d_in, const int* in_sizes, int n_in,
                              void* d_out, int out_size, void* d_ws, size_t ws_size,
                              hipStream_t stream)
{
  const void* hidden = d_in[0];
  const int*  pos    = (const int*)d_in[1];
  const int*  qkv_qw = (const int*)d_in[2];
  const int*  qkv_qz = (const int*)d_in[3];
  const void* qkv_sc = d_in[4];
  const void* qkv_bs = d_in[5];
  const int*  o_qw   = (const int*)d_in[6];
  const int*  o_qz   = (const int*)d_in[7];
  const void* o_sc   = d_in[8];

  char* ws = (char*)d_ws;
  unsigned short* qkvb   = (unsigned short*)ws;               // [2048][4608]
  unsigned short* attnb  = (unsigned short*)(ws + 18874368);  // [2048][3584]
  unsigned short* wscr1  = attnb;                             // [2304][3584] chunks
  unsigned short* part1  = (unsigned short*)(ws + 35389440);  // [224][16384]
  float*          mlbuf  = (float*)(ws + 42729472);           // [224][512]
  int*            flag   = (int*)(ws + 43188224);
  unsigned short* scbf1  = (unsigned short*)(ws + 43188240);  // [28][4608]
  unsigned short* scbf2  = (unsigned short*)(ws + 43446288);  // [28][3584]
  unsigned short* biasbf = (unsigned short*)(ws + 43646992);  // [4608]
  unsigned short* hidbf  = (unsigned short*)d_out;            // [2048][3584] scratch
  unsigned short* wscr2  = qkvb;                              // o-weight chunks [1792][3584]

  detect_dtype<<<1, 256, 0, stream>>>((const unsigned short*)hidden, flag);
  convert_bf<<<28672, 256, 0, stream>>>(hidden, hidbf, flag);
  convert_bf<<<504, 256, 0, stream>>>(qkv_sc, scbf1, flag);
  convert_bf<<<18, 256, 0, stream>>>(qkv_bs, biasbf, flag);
  convert_bf<<<392, 256, 0, stream>>>(o_sc, scbf2, flag);

  // QKV: 2 chunks of 2304 output cols (288 word-cols)
  for (int c = 0; c < 2; ++c) {
    dequant_awq<<<4032, 256, 0, stream>>>(
        qkv_qw + c * 288, qkv_qz + c * 288, scbf1 + c * 2304, wscr1,
        3584, 288, 576, 4608);
    gemm_bt<<<dim3(18, 16), 256, 0, stream>>>(
        hidbf, wscr1, biasbf + c * 2304, qkvb, c * 2304, 4608, 3584, nullptr);
  }
  rope_kernel<<<16384, 256, 0, stream>>>(qkvb, pos);
  attn_kernel<<<672, 256, 0, stream>>>(qkvb, attnb, part1, mlbuf);
  combine_kernel<<<224, 256, 0, stream>>>(attnb, part1, mlbuf);
  // O-proj: 2 chunks of 1792 output cols (224 word-cols)
  for (int c = 0; c < 2; ++c) {
    dequant_awq<<<3136, 256, 0, stream>>>(
        o_qw + c * 224, o_qz + c * 224, scbf2 + c * 1792, wscr2,
        3584, 224, 448, 3584);
    gemm_bt<<<dim3(14, 16), 256, 0, stream>>>(
        attnb, wscr2, nullptr, d_out, c * 1792, 3584, 3584, flag);
  }
}

// Round 5
// 449.153 us; speedup vs baseline: 1.7886x; 1.4722x over previous
//
#include <hip/hip_runtime.h>
#include <stdint.h>

// ---------------------------------------------------------------------------
// Qwen2-7B attention block on gfx950.
// R5: attention in transposed formulation (S^T / O^T): 2 shuffles per iter
//     instead of 32, packed b64 P stores, register prefetch of next K/V tile.
//     GEMM single-launch when ws_size allows (adaptive layout), else R4 chunks.
// ---------------------------------------------------------------------------

typedef short vshort4 __attribute__((ext_vector_type(4)));
typedef short vshort8 __attribute__((ext_vector_type(8)));
typedef __bf16 vbf16x8 __attribute__((ext_vector_type(8)));
typedef float vfloat4 __attribute__((ext_vector_type(4)));

#define SEQ 2048
#define NH 28
#define KVH 4
#define HD 128
#define QSZ 3584
#define QKV_N 4608
#define SM_SCALE 0.08838834764831845f

__device__ __forceinline__ float bf2f(unsigned short h) {
  union { unsigned int u; float f; } x; x.u = ((unsigned int)h) << 16; return x.f;
}
__device__ __forceinline__ unsigned short f2bf(float f) {
  union { unsigned int u; float f; } x; x.f = f;
  x.u += 0x7fff + ((x.u >> 16) & 1);
  return (unsigned short)(x.u >> 16);
}
__device__ __forceinline__ vbf16x8 ld_frag(const unsigned short* p) {
  return __builtin_bit_cast(vbf16x8, *(const vshort8*)p);
}
__device__ __forceinline__ vfloat4 mfma16(vbf16x8 a, vbf16x8 b, vfloat4 c) {
  return __builtin_amdgcn_mfma_f32_16x16x32_bf16(a, b, c, 0, 0, 0);
}
__device__ __forceinline__ void async_cp16(const unsigned short* g, unsigned short* l) {
  __builtin_amdgcn_global_load_lds((const __attribute__((address_space(1))) void*)g,
                                   (__attribute__((address_space(3))) void*)l, 16, 0, 0);
}
__device__ __forceinline__ vshort4 pack4(float a, float b, float c, float d) {
  vshort4 r; r[0] = (short)f2bf(a); r[1] = (short)f2bf(b);
  r[2] = (short)f2bf(c); r[3] = (short)f2bf(d); return r;
}

// ---------------------------------------------------------------------------
__global__ __launch_bounds__(256) void detect_dtype(
    const unsigned short* __restrict__ h, int* __restrict__ flag)
{
  __shared__ int red[256];
  int cnt = 0;
#pragma unroll
  for (int i = 0; i < 8; ++i) {
    unsigned short u = h[threadIdx.x * 8 + i];
    int e = (u >> 7) & 0xFF;
    cnt += (e >= 100 && e <= 150) ? 1 : 0;
  }
  red[threadIdx.x] = cnt;
  __syncthreads();
  for (int s = 128; s > 0; s >>= 1) {
    if (threadIdx.x < s) red[threadIdx.x] += red[threadIdx.x + s];
    __syncthreads();
  }
  if (threadIdx.x == 0) flag[0] = (red[0] >= 1700) ? 1 : 0;
}

__global__ __launch_bounds__(256) void convert_bf(
    const void* __restrict__ src, unsigned short* __restrict__ dst,
    const int* __restrict__ flag)
{
  int i = blockIdx.x * 256 + threadIdx.x;
  if (flag[0]) dst[i] = ((const unsigned short*)src)[i];
  else         dst[i] = f2bf(((const float*)src)[i]);
}

// ---------------------------------------------------------------------------
__global__ __launch_bounds__(256) void dequant_awq(
    const int* __restrict__ qw, const int* __restrict__ qz,
    const unsigned short* __restrict__ scales,
    unsigned short* __restrict__ Wt,
    int Kdim, int CwChunk, int CwStride, int NoutStride)
{
  int idx = blockIdx.x * 256 + threadIdx.x;
  int k = idx % Kdim;
  int c = idx / Kdim;
  int g = k >> 7;
  int w = qw[(size_t)k * CwStride + c];
  int z = qz[(size_t)g * CwStride + c];
#pragma unroll
  for (int j = 0; j < 8; ++j) {
    int wn = (w >> (4 * j)) & 0xF;
    int zn = (z >> (4 * j)) & 0xF;
    float s = bf2f(scales[(size_t)g * NoutStride + c * 8 + j]);
    Wt[(size_t)(c * 8 + j) * Kdim + k] = f2bf((float)(wn - zn) * s);
  }
}

// ---------------------------------------------------------------------------
// m97-style bf16 GEMM with global_load_lds width-16 staging.
// ---------------------------------------------------------------------------
__global__ __launch_bounds__(256) void gemm_bt(
    const unsigned short* __restrict__ A,
    const unsigned short* __restrict__ Bt,
    const unsigned short* __restrict__ bias,
    void* __restrict__ Cv, int n_base, int ldc, int K,
    const int* __restrict__ oflag)
{
  __shared__ __align__(16) unsigned short As[128 * 32];
  __shared__ __align__(16) unsigned short Bs[128 * 32];
  const int tid = threadIdx.x;
  const int w = tid >> 6, lane = tid & 63;
  const int c16 = lane & 15, q4 = lane >> 4;
  const int m0 = blockIdx.y * 128, n0 = blockIdx.x * 128;
  const int wr = (w >> 1) * 64, wc = (w & 1) * 64;

  vfloat4 acc[4][4];
#pragma unroll
  for (int i = 0; i < 4; ++i)
#pragma unroll
    for (int j = 0; j < 4; ++j) { vfloat4 z = {0.f, 0.f, 0.f, 0.f}; acc[i][j] = z; }

  const unsigned short* aP0 = A  + (size_t)(m0 + (tid >> 2)) * K + (tid & 3) * 8;
  const unsigned short* aP1 = A  + (size_t)(m0 + 64 + (tid >> 2)) * K + (tid & 3) * 8;
  const unsigned short* bP0 = Bt + (size_t)(n0 + (tid >> 2)) * K + (tid & 3) * 8;
  const unsigned short* bP1 = Bt + (size_t)(n0 + 64 + (tid >> 2)) * K + (tid & 3) * 8;
  unsigned short* lA0 = As + (w * 64) * 8;
  unsigned short* lA1 = As + (256 + w * 64) * 8;
  unsigned short* lB0 = Bs + (w * 64) * 8;
  unsigned short* lB1 = Bs + (256 + w * 64) * 8;

  for (int k0 = 0; k0 < K; k0 += 32) {
    async_cp16(aP0, lA0);
    async_cp16(aP1, lA1);
    async_cp16(bP0, lB0);
    async_cp16(bP1, lB1);
    aP0 += 32; aP1 += 32; bP0 += 32; bP1 += 32;
    __builtin_amdgcn_s_waitcnt(0);
    __syncthreads();
    vbf16x8 af[4], bf[4];
#pragma unroll
    for (int i = 0; i < 4; ++i) af[i] = ld_frag(As + (wr + i * 16 + c16) * 32 + q4 * 8);
#pragma unroll
    for (int j = 0; j < 4; ++j) bf[j] = ld_frag(Bs + (wc + j * 16 + c16) * 32 + q4 * 8);
#pragma unroll
    for (int i = 0; i < 4; ++i)
#pragma unroll
      for (int j = 0; j < 4; ++j)
        acc[i][j] = mfma16(af[i], bf[j], acc[i][j]);
    __syncthreads();
  }

  const int bfm = (oflag == nullptr) ? 1 : oflag[0];
#pragma unroll
  for (int i = 0; i < 4; ++i) {
    int m = m0 + wr + i * 16 + q4 * 4;
#pragma unroll
    for (int j = 0; j < 4; ++j) {
      int n = wc + j * 16 + c16 + n0;
      float bv = bias ? bf2f(bias[n]) : 0.f;
#pragma unroll
      for (int r = 0; r < 4; ++r) {
        float v = acc[i][j][r] + bv;
        size_t idx = (size_t)(m + r) * ldc + n + n_base;
        if (bfm) ((unsigned short*)Cv)[idx] = f2bf(v);
        else     ((float*)Cv)[idx] = v;
      }
    }
  }
}

// ---------------------------------------------------------------------------
__global__ __launch_bounds__(256) void rope_kernel(
    unsigned short* __restrict__ qkv, const int* __restrict__ pos)
{
  int idx = blockIdx.x * 256 + threadIdx.x;
  int j = idx & 63;
  int h2 = (idx >> 6) & 31;
  int s = idx >> 11;
  unsigned short* row = qkv + (size_t)s * QKV_N;
  int col = (h2 < NH) ? (h2 * HD + j) : (QSZ + (h2 - NH) * HD + j);
  float inv = exp2f(-(float)j * 0.31143079014569017f);
  float ang = (float)pos[s] * inv;
  float sn, cs;
  sincosf(ang, &sn, &cs);
  float x1 = bf2f(row[col]);
  float x2 = bf2f(row[col + 64]);
  row[col]      = f2bf(x1 * cs - x2 * sn);
  row[col + 64] = f2bf(x2 * cs + x1 * sn);
}

// ---------------------------------------------------------------------------
// GQA causal flash attention, transposed formulation.
// S^T = mfma(Kfrag, Qfrag): lane holds one q-col (c16), keys in q4*4+r.
// Row-softmax: per-lane max over 16 vals + 2 shuffles (xor16, xor32).
// O^T = mfma(Vfrag, Pfrag); l via ones-A MFMA. Register prefetch of next K/V.
// Split-K 2-way for qt>=8 (same mapping as R4).
// ---------------------------------------------------------------------------
__global__ __launch_bounds__(256, 2) void attn_kernel(
    const unsigned short* __restrict__ qkv,   // [SEQ][4608] post-rope
    unsigned short* __restrict__ attnb,       // [SEQ][3584]
    unsigned short* __restrict__ part1,       // [224][128][128] chunk-1 partials
    float* __restrict__ ml)                   // [224][128][4]
{
  __shared__ __align__(16) unsigned short kvK[64 * 136];
  __shared__ __align__(16) unsigned short kvV[128 * 72];
  __shared__ __align__(16) unsigned short pb[4 * 32 * 72];
  const int tid = threadIdx.x, w = tid >> 6, lane = tid & 63;
  const int c16 = lane & 15, q4 = lane >> 4;

  int bid = blockIdx.x;
  int h, qt, chunk, kt0, kt1, t = 0;
  if (bid < 448) {
    h = bid >> 4; int s = bid & 15;
    qt = 15 - (s >> 1); chunk = s & 1;
    int half = qt + 1;
    kt0 = chunk * half; kt1 = kt0 + half;
    t = h * 8 + (qt - 8);
  } else {
    int d = bid - 448; h = d >> 3; qt = 7 - (d & 7); chunk = -1;
    kt0 = 0; kt1 = 2 * (qt + 1);
  }
  const int q0 = qt * 128;
  const int kvh = h / 7;
  unsigned short* pw = pb + w * 2304;

  // Q fragments (B-operand): lane n=c16 -> q-row, k = kk*32 + q4*8
  vbf16x8 qf[2][4];
#pragma unroll
  for (int i = 0; i < 2; ++i)
#pragma unroll
    for (int kk = 0; kk < 4; ++kk)
      qf[i][kk] = ld_frag(qkv + (size_t)(q0 + w * 32 + i * 16 + c16) * QKV_N
                          + h * HD + kk * 32 + q4 * 8);

  vfloat4 of[2][8];   // O^T: [q-tile i][d-tile jd]; lane: q=c16, d=q4*4+r
  vfloat4 ofl[2];     // l per q (all regs equal)
  float m_run[2];
#pragma unroll
  for (int i = 0; i < 2; ++i) {
    m_run[i] = -1e30f;
    vfloat4 z = {0.f, 0.f, 0.f, 0.f};
    ofl[i] = z;
#pragma unroll
    for (int j = 0; j < 8; ++j) of[i][j] = z;
  }
  const vshort8 ones_s = {(short)0x3F80, (short)0x3F80, (short)0x3F80, (short)0x3F80,
                          (short)0x3F80, (short)0x3F80, (short)0x3F80, (short)0x3F80};
  const vbf16x8 onesf = __builtin_bit_cast(vbf16x8, ones_s);

  // prefetch registers for K/V staging
  vshort8 kreg[4], vreg[4];
#pragma unroll
  for (int it = 0; it < 4; ++it) {
    int ch = it * 256 + tid;
    kreg[it] = *(const vshort8*)(qkv + (size_t)(kt0 * 64 + (ch >> 4)) * QKV_N
                                 + QSZ + kvh * HD + (ch & 15) * 8);
    vreg[it] = *(const vshort8*)(qkv + (size_t)(kt0 * 64 + lane) * QKV_N
                                 + QSZ + 512 + kvh * HD + (it * 4 + w) * 8);
  }

  for (int kt = kt0; kt < kt1; ++kt) {
    const int k0 = kt * 64;
    __syncthreads();  // prior-iter LDS reads complete
#pragma unroll
    for (int it = 0; it < 4; ++it) {
      int ch = it * 256 + tid;
      *(vshort8*)(kvK + (ch >> 4) * 136 + (ch & 15) * 8) = kreg[it];
    }
#pragma unroll
    for (int it = 0; it < 4; ++it) {
      int sub = it * 4 + w;
#pragma unroll
      for (int jj = 0; jj < 8; ++jj)
        kvV[(sub * 8 + jj) * 72 + lane] = (unsigned short)vreg[it][jj];
    }
    __syncthreads();
    if (kt + 1 < kt1) {  // wave-uniform
#pragma unroll
      for (int it = 0; it < 4; ++it) {
        int ch = it * 256 + tid;
        kreg[it] = *(const vshort8*)(qkv + (size_t)((kt + 1) * 64 + (ch >> 4)) * QKV_N
                                     + QSZ + kvh * HD + (ch & 15) * 8);
        vreg[it] = *(const vshort8*)(qkv + (size_t)((kt + 1) * 64 + lane) * QKV_N
                                     + QSZ + 512 + kvh * HD + (it * 4 + w) * 8);
      }
    }

    // S^T[key][q] = mfma(Kfrag, Qfrag)
    vfloat4 st[2][4];
#pragma unroll
    for (int i = 0; i < 2; ++i)
#pragma unroll
      for (int j = 0; j < 4; ++j) { vfloat4 z = {0.f, 0.f, 0.f, 0.f}; st[i][j] = z; }
#pragma unroll
    for (int j = 0; j < 4; ++j)
#pragma unroll
      for (int kk = 0; kk < 4; ++kk) {
        vbf16x8 kf = ld_frag(kvK + (j * 16 + c16) * 136 + kk * 32 + q4 * 8);
        st[0][j] = mfma16(kf, qf[0][kk], st[0][j]);
        st[1][j] = mfma16(kf, qf[1][kk], st[1][j]);
      }

    // scale + causal + online softmax (per-lane row; 2 shuffles)
    float alpha[2];
#pragma unroll
    for (int i = 0; i < 2; ++i) {
      const int qcol = q0 + w * 32 + i * 16 + c16;
      float mx = -1e30f;
#pragma unroll
      for (int j = 0; j < 4; ++j)
#pragma unroll
        for (int r = 0; r < 4; ++r) {
          int key = k0 + j * 16 + q4 * 4 + r;
          float v = st[i][j][r] * SM_SCALE;
          v = (key > qcol) ? -1e30f : v;
          st[i][j][r] = v;
          mx = fmaxf(mx, v);
        }
      mx = fmaxf(mx, __shfl_xor(mx, 16));
      mx = fmaxf(mx, __shfl_xor(mx, 32));
      float mold = m_run[i];
      float mn = fmaxf(mold, mx);
      alpha[i] = __expf(mold - mn);
      m_run[i] = mn;
#pragma unroll
      for (int j = 0; j < 4; ++j)
#pragma unroll
        for (int r = 0; r < 4; ++r)
          st[i][j][r] = __expf(st[i][j][r] - mn);
    }
    // rescale O^T and l
#pragma unroll
    for (int i = 0; i < 2; ++i) {
#pragma unroll
      for (int j = 0; j < 8; ++j)
#pragma unroll
        for (int r = 0; r < 4; ++r)
          of[i][j][r] *= alpha[i];
#pragma unroll
      for (int r = 0; r < 4; ++r) ofl[i][r] *= alpha[i];
    }
    // P[q][key] -> per-wave LDS, packed b64 (4 keys per store)
#pragma unroll
    for (int i = 0; i < 2; ++i)
#pragma unroll
      for (int j = 0; j < 4; ++j)
        *(vshort4*)(pw + (i * 16 + c16) * 72 + j * 16 + q4 * 4) =
            pack4(st[i][j][0], st[i][j][1], st[i][j][2], st[i][j][3]);

    // O^T += mfma(Vfrag, Pfrag); l += mfma(ones, Pfrag)
#pragma unroll
    for (int kk = 0; kk < 2; ++kk) {
      vbf16x8 p0 = ld_frag(pw + (c16) * 72 + kk * 32 + q4 * 8);
      vbf16x8 p1 = ld_frag(pw + (16 + c16) * 72 + kk * 32 + q4 * 8);
#pragma unroll
      for (int jd = 0; jd < 8; ++jd) {
        vbf16x8 vf = ld_frag(kvV + (jd * 16 + c16) * 72 + kk * 32 + q4 * 8);
        of[0][jd] = mfma16(vf, p0, of[0][jd]);
        of[1][jd] = mfma16(vf, p1, of[1][jd]);
      }
      ofl[0] = mfma16(onesf, p0, ofl[0]);
      ofl[1] = mfma16(onesf, p1, ofl[1]);
    }
  }

  // epilogue: lane holds q = c16 (+tile), d = jd*16 + q4*4 + r -> b64 stores
#pragma unroll
  for (int i = 0; i < 2; ++i) {
    int lr = w * 32 + i * 16 + c16;
    int qrow = q0 + lr;
    float l = ofl[i][0];
    if (chunk < 0) {
      float inv_l = 1.f / l;
#pragma unroll
      for (int jd = 0; jd < 8; ++jd)
        *(vshort4*)(attnb + (size_t)qrow * QSZ + h * HD + jd * 16 + q4 * 4) =
            pack4(of[i][jd][0] * inv_l, of[i][jd][1] * inv_l,
                  of[i][jd][2] * inv_l, of[i][jd][3] * inv_l);
    } else if (chunk == 0) {
#pragma unroll
      for (int jd = 0; jd < 8; ++jd)
        *(vshort4*)(attnb + (size_t)qrow * QSZ + h * HD + jd * 16 + q4 * 4) =
            pack4(of[i][jd][0], of[i][jd][1], of[i][jd][2], of[i][jd][3]);
      if (q4 == 0) { ml[t * 512 + lr * 4 + 0] = m_run[i]; ml[t * 512 + lr * 4 + 1] = l; }
    } else {
#pragma unroll
      for (int jd = 0; jd < 8; ++jd)
        *(vshort4*)(part1 + (size_t)t * 16384 + lr * 128 + jd * 16 + q4 * 4) =
            pack4(of[i][jd][0], of[i][jd][1], of[i][jd][2], of[i][jd][3]);
      if (q4 == 0) { ml[t * 512 + lr * 4 + 2] = m_run[i]; ml[t * 512 + lr * 4 + 3] = l; }
    }
  }
}

// ---------------------------------------------------------------------------
__global__ __launch_bounds__(256) void combine_kernel(
    unsigned short* __restrict__ attnb, const unsigned short* __restrict__ part1,
    const float* __restrict__ ml)
{
  int t = blockIdx.x;
  int h = t >> 3, qt = (t & 7) + 8;
  int lr = threadIdx.x >> 1, ch = (threadIdx.x & 1) * 64;
  int row = qt * 128 + lr;
  float m0 = ml[t * 512 + lr * 4 + 0], l0 = ml[t * 512 + lr * 4 + 1];
  float m1 = ml[t * 512 + lr * 4 + 2], l1 = ml[t * 512 + lr * 4 + 3];
  float M = fmaxf(m0, m1);
  float w0 = __expf(m0 - M), w1 = __expf(m1 - M);
  float inv = 1.f / (l0 * w0 + l1 * w1);
  unsigned short* dst = attnb + (size_t)row * QSZ + h * HD + ch;
  const unsigned short* src = part1 + (size_t)t * 16384 + lr * 128 + ch;
#pragma unroll
  for (int k = 0; k < 8; ++k) {
    vshort8 a = *(const vshort8*)(dst + k * 8);
    vshort8 b = *(const vshort8*)(src + k * 8);
    vshort8 o;
#pragma unroll
    for (int jj = 0; jj < 8; ++jj)
      o[jj] = (short)f2bf((bf2f((unsigned short)a[jj]) * w0 +
                           bf2f((unsigned short)b[jj]) * w1) * inv);
    *(vshort8*)(dst + k * 8) = o;
  }
}

// ---------------------------------------------------------------------------
extern "C" void kernel_launch(void* const* d_in, const int* in_sizes, int n_in,
                              void* d_out, int out_size, void* d_ws, size_t ws_size,
                              hipStream_t stream)
{
  const void* hidden = d_in[0];
  const int*  pos    = (const int*)d_in[1];
  const int*  qkv_qw = (const int*)d_in[2];
  const int*  qkv_qz = (const int*)d_in[3];
  const void* qkv_sc = d_in[4];
  const void* qkv_bs = d_in[5];
  const int*  o_qw   = (const int*)d_in[6];
  const int*  o_qz   = (const int*)d_in[7];
  const void* o_sc   = d_in[8];

  char* ws = (char*)d_ws;
  unsigned short* hidbf = (unsigned short*)d_out;  // dead once gemm1 done

  if (ws_size >= 67052560ULL) {
    // ------- big layout: single-launch GEMMs -------
    unsigned short* qkvb   = (unsigned short*)ws;               // [2048][4608]
    unsigned short* attnb  = (unsigned short*)(ws + 18874368);  // [2048][3584]
    unsigned short* W      = (unsigned short*)(ws + 33554432);  // weights region 33 MB
    unsigned short* part1  = W;                                  // after gemm1
    float*          mlbuf  = (float*)(ws + 33554432 + 7340032);
    unsigned short* scbf1  = (unsigned short*)(ws + 66584576);
    unsigned short* scbf2  = (unsigned short*)(ws + 66842624);
    unsigned short* biasbf = (unsigned short*)(ws + 67043328);
    int*            flag   = (int*)(ws + 67052544);

    detect_dtype<<<1, 256, 0, stream>>>((const unsigned short*)hidden, flag);
    convert_bf<<<28672, 256, 0, stream>>>(hidden, hidbf, flag);
    convert_bf<<<504, 256, 0, stream>>>(qkv_sc, scbf1, flag);
    convert_bf<<<18, 256, 0, stream>>>(qkv_bs, biasbf, flag);
    convert_bf<<<392, 256, 0, stream>>>(o_sc, scbf2, flag);

    dequant_awq<<<8064, 256, 0, stream>>>(qkv_qw, qkv_qz, scbf1, W, 3584, 576, 576, 4608);
    gemm_bt<<<dim3(36, 16), 256, 0, stream>>>(hidbf, W, biasbf, qkvb, 0, 4608, 3584, nullptr);
    rope_kernel<<<16384, 256, 0, stream>>>(qkvb, pos);
    attn_kernel<<<672, 256, 0, stream>>>(qkvb, attnb, part1, mlbuf);
    combine_kernel<<<224, 256, 0, stream>>>(attnb, part1, mlbuf);
    dequant_awq<<<6272, 256, 0, stream>>>(o_qw, o_qz, scbf2, W, 3584, 448, 448, 3584);
    gemm_bt<<<dim3(28, 16), 256, 0, stream>>>(attnb, W, nullptr, d_out, 0, 3584, 3584, flag);
  } else {
    // ------- R4 chunked fallback (known-safe 43.7 MB) -------
    unsigned short* qkvb   = (unsigned short*)ws;               // [2048][4608]
    unsigned short* attnb  = (unsigned short*)(ws + 18874368);  // [2048][3584]
    unsigned short* wscr1  = attnb;                             // [2304][3584]
    unsigned short* part1  = (unsigned short*)(ws + 35389440);  // [224][16384]
    float*          mlbuf  = (float*)(ws + 42729472);           // [224][512]
    int*            flag   = (int*)(ws + 43188224);
    unsigned short* scbf1  = (unsigned short*)(ws + 43188240);
    unsigned short* scbf2  = (unsigned short*)(ws + 43446288);
    unsigned short* biasbf = (unsigned short*)(ws + 43646992);
    unsigned short* wscr2  = qkvb;

    detect_dtype<<<1, 256, 0, stream>>>((const unsigned short*)hidden, flag);
    convert_bf<<<28672, 256, 0, stream>>>(hidden, hidbf, flag);
    convert_bf<<<504, 256, 0, stream>>>(qkv_sc, scbf1, flag);
    convert_bf<<<18, 256, 0, stream>>>(qkv_bs, biasbf, flag);
    convert_bf<<<392, 256, 0, stream>>>(o_sc, scbf2, flag);

    for (int c = 0; c < 2; ++c) {
      dequant_awq<<<4032, 256, 0, stream>>>(
          qkv_qw + c * 288, qkv_qz + c * 288, scbf1 + c * 2304, wscr1,
          3584, 288, 576, 4608);
      gemm_bt<<<dim3(18, 16), 256, 0, stream>>>(
          hidbf, wscr1, biasbf + c * 2304, qkvb, c * 2304, 4608, 3584, nullptr);
    }
    rope_kernel<<<16384, 256, 0, stream>>>(qkvb, pos);
    attn_kernel<<<672, 256, 0, stream>>>(qkvb, attnb, part1, mlbuf);
    combine_kernel<<<224, 256, 0, stream>>>(attnb, part1, mlbuf);
    for (int c = 0; c < 2; ++c) {
      dequant_awq<<<3136, 256, 0, stream>>>(
          o_qw + c * 224, o_qz + c * 224, scbf2 + c * 1792, wscr2,
          3584, 224, 448, 3584);
      gemm_bt<<<dim3(14, 16), 256, 0, stream>>>(
          attnb, wscr2, nullptr, d_out, c * 1792, 3584, 3584, flag);
    }
  }
}

// Round 6
// 437.119 us; speedup vs baseline: 1.8378x; 1.0275x over previous
//
#include <hip/hip_runtime.h>
#include <stdint.h>

// ---------------------------------------------------------------------------
// Qwen2-7B attention block on gfx950.
// R6: GEMM LDS XOR-swizzle (kills 8-way frag-read bank conflicts; DMA-safe
//     because only the global source per slot is permuted), 4-k packed
//     dequant with b64 stores, vectorized bf16 converts.
// ---------------------------------------------------------------------------

typedef short vshort4 __attribute__((ext_vector_type(4)));
typedef short vshort8 __attribute__((ext_vector_type(8)));
typedef __bf16 vbf16x8 __attribute__((ext_vector_type(8)));
typedef float vfloat4 __attribute__((ext_vector_type(4)));

#define SEQ 2048
#define NH 28
#define KVH 4
#define HD 128
#define QSZ 3584
#define QKV_N 4608
#define SM_SCALE 0.08838834764831845f

__device__ __forceinline__ float bf2f(unsigned short h) {
  union { unsigned int u; float f; } x; x.u = ((unsigned int)h) << 16; return x.f;
}
__device__ __forceinline__ unsigned short f2bf(float f) {
  union { unsigned int u; float f; } x; x.f = f;
  x.u += 0x7fff + ((x.u >> 16) & 1);
  return (unsigned short)(x.u >> 16);
}
__device__ __forceinline__ vbf16x8 ld_frag(const unsigned short* p) {
  return __builtin_bit_cast(vbf16x8, *(const vshort8*)p);
}
__device__ __forceinline__ vfloat4 mfma16(vbf16x8 a, vbf16x8 b, vfloat4 c) {
  return __builtin_amdgcn_mfma_f32_16x16x32_bf16(a, b, c, 0, 0, 0);
}
__device__ __forceinline__ void async_cp16(const unsigned short* g, unsigned short* l) {
  __builtin_amdgcn_global_load_lds((const __attribute__((address_space(1))) void*)g,
                                   (__attribute__((address_space(3))) void*)l, 16, 0, 0);
}
__device__ __forceinline__ vshort4 pack4(float a, float b, float c, float d) {
  vshort4 r; r[0] = (short)f2bf(a); r[1] = (short)f2bf(b);
  r[2] = (short)f2bf(c); r[3] = (short)f2bf(d); return r;
}

// ---------------------------------------------------------------------------
__global__ __launch_bounds__(256) void detect_dtype(
    const unsigned short* __restrict__ h, int* __restrict__ flag)
{
  __shared__ int red[256];
  int cnt = 0;
#pragma unroll
  for (int i = 0; i < 8; ++i) {
    unsigned short u = h[threadIdx.x * 8 + i];
    int e = (u >> 7) & 0xFF;
    cnt += (e >= 100 && e <= 150) ? 1 : 0;
  }
  red[threadIdx.x] = cnt;
  __syncthreads();
  for (int s = 128; s > 0; s >>= 1) {
    if (threadIdx.x < s) red[threadIdx.x] += red[threadIdx.x + s];
    __syncthreads();
  }
  if (threadIdx.x == 0) flag[0] = (red[0] >= 1700) ? 1 : 0;
}

__global__ __launch_bounds__(256) void convert_bf(
    const void* __restrict__ src, unsigned short* __restrict__ dst,
    const int* __restrict__ flag)
{
  int i = blockIdx.x * 256 + threadIdx.x;
  if (flag[0]) dst[i] = ((const unsigned short*)src)[i];
  else         dst[i] = f2bf(((const float*)src)[i]);
}

// vectorized x8 variant (n must be a multiple of 2048)
__global__ __launch_bounds__(256) void convert_bf8(
    const void* __restrict__ src, unsigned short* __restrict__ dst,
    const int* __restrict__ flag)
{
  int i = (blockIdx.x * 256 + threadIdx.x) * 8;
  if (flag[0]) {
    *(vshort8*)(dst + i) = *(const vshort8*)((const unsigned short*)src + i);
  } else {
    const float* s = (const float*)src + i;
    float4 a = *(const float4*)s;
    float4 b = *(const float4*)(s + 4);
    vshort8 o;
    o[0] = (short)f2bf(a.x); o[1] = (short)f2bf(a.y);
    o[2] = (short)f2bf(a.z); o[3] = (short)f2bf(a.w);
    o[4] = (short)f2bf(b.x); o[5] = (short)f2bf(b.y);
    o[6] = (short)f2bf(b.z); o[7] = (short)f2bf(b.w);
    *(vshort8*)(dst + i) = o;
  }
}

// ---------------------------------------------------------------------------
// AWQ int4 dequant, 4-k packed: thread handles (c, k4) -> 8 cols x 4 k's,
// b64 stores. Kdim/4 is a multiple of 64 so waves have uniform c.
// ---------------------------------------------------------------------------
__global__ __launch_bounds__(256) void dequant_awq(
    const int* __restrict__ qw, const int* __restrict__ qz,
    const unsigned short* __restrict__ scales,
    unsigned short* __restrict__ Wt,
    int Kdim, int CwChunk, int CwStride, int NoutStride)
{
  int idx = blockIdx.x * 256 + threadIdx.x;   // total = (Kdim/4)*CwChunk
  int kq = Kdim >> 2;
  int k4 = idx % kq;
  int c  = idx / kq;
  int k  = k4 * 4;
  int g  = k >> 7;
  int w0 = qw[(size_t)(k + 0) * CwStride + c];
  int w1 = qw[(size_t)(k + 1) * CwStride + c];
  int w2 = qw[(size_t)(k + 2) * CwStride + c];
  int w3 = qw[(size_t)(k + 3) * CwStride + c];
  int z  = qz[(size_t)g * CwStride + c];
#pragma unroll
  for (int j = 0; j < 8; ++j) {
    int sh = 4 * j;
    float zn = (float)((z >> sh) & 0xF);
    float s  = bf2f(scales[(size_t)g * NoutStride + c * 8 + j]);
    vshort4 o;
    o[0] = (short)f2bf(((float)((w0 >> sh) & 0xF) - zn) * s);
    o[1] = (short)f2bf(((float)((w1 >> sh) & 0xF) - zn) * s);
    o[2] = (short)f2bf(((float)((w2 >> sh) & 0xF) - zn) * s);
    o[3] = (short)f2bf(((float)((w3 >> sh) & 0xF) - zn) * s);
    *(vshort4*)(Wt + (size_t)(c * 8 + j) * Kdim + k) = o;
  }
}

// ---------------------------------------------------------------------------
// m97-style bf16 GEMM, XOR-swizzled LDS.
// Slot s (16B) holds (row = s>>2, gsub = (s&3) ^ ((row>>1)&3)); DMA writes
// slots linearly, global source per lane uses gsub. Frag read for (row, q4)
// at byte offset row*64 + (q4 ^ ((row>>1)&3))*16 -> 2-way worst case.
// ---------------------------------------------------------------------------
__global__ __launch_bounds__(256) void gemm_bt(
    const unsigned short* __restrict__ A,
    const unsigned short* __restrict__ Bt,
    const unsigned short* __restrict__ bias,
    void* __restrict__ Cv, int n_base, int ldc, int K,
    const int* __restrict__ oflag)
{
  __shared__ __align__(16) unsigned short As[128 * 32];
  __shared__ __align__(16) unsigned short Bs[128 * 32];
  const int tid = threadIdx.x;
  const int w = tid >> 6, lane = tid & 63;
  const int c16 = lane & 15, q4 = lane >> 4;
  const int m0 = blockIdx.y * 128, n0 = blockIdx.x * 128;
  const int wr = (w >> 1) * 64, wc = (w & 1) * 64;

  vfloat4 acc[4][4];
#pragma unroll
  for (int i = 0; i < 4; ++i)
#pragma unroll
    for (int j = 0; j < 4; ++j) { vfloat4 z = {0.f, 0.f, 0.f, 0.f}; acc[i][j] = z; }

  // staging: slot = tid (rows 0-63) / 256+tid (rows 64-127); swizzled source
  const int srow = tid >> 2;
  const int gsub = (tid & 3) ^ ((tid >> 3) & 3);
  const unsigned short* aP0 = A  + (size_t)(m0 + srow) * K + gsub * 8;
  const unsigned short* aP1 = A  + (size_t)(m0 + 64 + srow) * K + gsub * 8;
  const unsigned short* bP0 = Bt + (size_t)(n0 + srow) * K + gsub * 8;
  const unsigned short* bP1 = Bt + (size_t)(n0 + 64 + srow) * K + gsub * 8;
  unsigned short* lA0 = As + (w * 64) * 8;
  unsigned short* lA1 = As + (256 + w * 64) * 8;
  unsigned short* lB0 = Bs + (w * 64) * 8;
  unsigned short* lB1 = Bs + (256 + w * 64) * 8;

  // loop-invariant swizzled frag-read offsets
  int offA[4], offB[4];
#pragma unroll
  for (int i = 0; i < 4; ++i) {
    int ra = wr + i * 16 + c16;
    offA[i] = ra * 32 + (q4 ^ ((ra >> 1) & 3)) * 8;
    int rb = wc + i * 16 + c16;
    offB[i] = rb * 32 + (q4 ^ ((rb >> 1) & 3)) * 8;
  }

  for (int k0 = 0; k0 < K; k0 += 32) {
    async_cp16(aP0, lA0);
    async_cp16(aP1, lA1);
    async_cp16(bP0, lB0);
    async_cp16(bP1, lB1);
    aP0 += 32; aP1 += 32; bP0 += 32; bP1 += 32;
    __builtin_amdgcn_s_waitcnt(0);
    __syncthreads();
    vbf16x8 af[4], bf[4];
#pragma unroll
    for (int i = 0; i < 4; ++i) af[i] = ld_frag(As + offA[i]);
#pragma unroll
    for (int j = 0; j < 4; ++j) bf[j] = ld_frag(Bs + offB[j]);
#pragma unroll
    for (int i = 0; i < 4; ++i)
#pragma unroll
      for (int j = 0; j < 4; ++j)
        acc[i][j] = mfma16(af[i], bf[j], acc[i][j]);
    __syncthreads();
  }

  const int bfm = (oflag == nullptr) ? 1 : oflag[0];
#pragma unroll
  for (int i = 0; i < 4; ++i) {
    int m = m0 + wr + i * 16 + q4 * 4;
#pragma unroll
    for (int j = 0; j < 4; ++j) {
      int n = wc + j * 16 + c16 + n0;
      float bv = bias ? bf2f(bias[n]) : 0.f;
#pragma unroll
      for (int r = 0; r < 4; ++r) {
        float v = acc[i][j][r] + bv;
        size_t idx = (size_t)(m + r) * ldc + n + n_base;
        if (bfm) ((unsigned short*)Cv)[idx] = f2bf(v);
        else     ((float*)Cv)[idx] = v;
      }
    }
  }
}

// ---------------------------------------------------------------------------
__global__ __launch_bounds__(256) void rope_kernel(
    unsigned short* __restrict__ qkv, const int* __restrict__ pos)
{
  int idx = blockIdx.x * 256 + threadIdx.x;
  int j = idx & 63;
  int h2 = (idx >> 6) & 31;
  int s = idx >> 11;
  unsigned short* row = qkv + (size_t)s * QKV_N;
  int col = (h2 < NH) ? (h2 * HD + j) : (QSZ + (h2 - NH) * HD + j);
  float inv = exp2f(-(float)j * 0.31143079014569017f);
  float ang = (float)pos[s] * inv;
  float sn, cs;
  sincosf(ang, &sn, &cs);
  float x1 = bf2f(row[col]);
  float x2 = bf2f(row[col + 64]);
  row[col]      = f2bf(x1 * cs - x2 * sn);
  row[col + 64] = f2bf(x2 * cs + x1 * sn);
}

// ---------------------------------------------------------------------------
// GQA causal flash attention, transposed formulation (unchanged from R5).
// ---------------------------------------------------------------------------
__global__ __launch_bounds__(256, 2) void attn_kernel(
    const unsigned short* __restrict__ qkv,
    unsigned short* __restrict__ attnb,
    unsigned short* __restrict__ part1,
    float* __restrict__ ml)
{
  __shared__ __align__(16) unsigned short kvK[64 * 136];
  __shared__ __align__(16) unsigned short kvV[128 * 72];
  __shared__ __align__(16) unsigned short pb[4 * 32 * 72];
  const int tid = threadIdx.x, w = tid >> 6, lane = tid & 63;
  const int c16 = lane & 15, q4 = lane >> 4;

  int bid = blockIdx.x;
  int h, qt, chunk, kt0, kt1, t = 0;
  if (bid < 448) {
    h = bid >> 4; int s = bid & 15;
    qt = 15 - (s >> 1); chunk = s & 1;
    int half = qt + 1;
    kt0 = chunk * half; kt1 = kt0 + half;
    t = h * 8 + (qt - 8);
  } else {
    int d = bid - 448; h = d >> 3; qt = 7 - (d & 7); chunk = -1;
    kt0 = 0; kt1 = 2 * (qt + 1);
  }
  const int q0 = qt * 128;
  const int kvh = h / 7;
  unsigned short* pw = pb + w * 2304;

  vbf16x8 qf[2][4];
#pragma unroll
  for (int i = 0; i < 2; ++i)
#pragma unroll
    for (int kk = 0; kk < 4; ++kk)
      qf[i][kk] = ld_frag(qkv + (size_t)(q0 + w * 32 + i * 16 + c16) * QKV_N
                          + h * HD + kk * 32 + q4 * 8);

  vfloat4 of[2][8];
  vfloat4 ofl[2];
  float m_run[2];
#pragma unroll
  for (int i = 0; i < 2; ++i) {
    m_run[i] = -1e30f;
    vfloat4 z = {0.f, 0.f, 0.f, 0.f};
    ofl[i] = z;
#pragma unroll
    for (int j = 0; j < 8; ++j) of[i][j] = z;
  }
  const vshort8 ones_s = {(short)0x3F80, (short)0x3F80, (short)0x3F80, (short)0x3F80,
                          (short)0x3F80, (short)0x3F80, (short)0x3F80, (short)0x3F80};
  const vbf16x8 onesf = __builtin_bit_cast(vbf16x8, ones_s);

  vshort8 kreg[4], vreg[4];
#pragma unroll
  for (int it = 0; it < 4; ++it) {
    int ch = it * 256 + tid;
    kreg[it] = *(const vshort8*)(qkv + (size_t)(kt0 * 64 + (ch >> 4)) * QKV_N
                                 + QSZ + kvh * HD + (ch & 15) * 8);
    vreg[it] = *(const vshort8*)(qkv + (size_t)(kt0 * 64 + lane) * QKV_N
                                 + QSZ + 512 + kvh * HD + (it * 4 + w) * 8);
  }

  for (int kt = kt0; kt < kt1; ++kt) {
    const int k0 = kt * 64;
    __syncthreads();
#pragma unroll
    for (int it = 0; it < 4; ++it) {
      int ch = it * 256 + tid;
      *(vshort8*)(kvK + (ch >> 4) * 136 + (ch & 15) * 8) = kreg[it];
    }
#pragma unroll
    for (int it = 0; it < 4; ++it) {
      int sub = it * 4 + w;
#pragma unroll
      for (int jj = 0; jj < 8; ++jj)
        kvV[(sub * 8 + jj) * 72 + lane] = (unsigned short)vreg[it][jj];
    }
    __syncthreads();
    if (kt + 1 < kt1) {
#pragma unroll
      for (int it = 0; it < 4; ++it) {
        int ch = it * 256 + tid;
        kreg[it] = *(const vshort8*)(qkv + (size_t)((kt + 1) * 64 + (ch >> 4)) * QKV_N
                                     + QSZ + kvh * HD + (ch & 15) * 8);
        vreg[it] = *(const vshort8*)(qkv + (size_t)((kt + 1) * 64 + lane) * QKV_N
                                     + QSZ + 512 + kvh * HD + (it * 4 + w) * 8);
      }
    }

    vfloat4 st[2][4];
#pragma unroll
    for (int i = 0; i < 2; ++i)
#pragma unroll
      for (int j = 0; j < 4; ++j) { vfloat4 z = {0.f, 0.f, 0.f, 0.f}; st[i][j] = z; }
#pragma unroll
    for (int j = 0; j < 4; ++j)
#pragma unroll
      for (int kk = 0; kk < 4; ++kk) {
        vbf16x8 kf = ld_frag(kvK + (j * 16 + c16) * 136 + kk * 32 + q4 * 8);
        st[0][j] = mfma16(kf, qf[0][kk], st[0][j]);
        st[1][j] = mfma16(kf, qf[1][kk], st[1][j]);
      }

    float alpha[2];
#pragma unroll
    for (int i = 0; i < 2; ++i) {
      const int qcol = q0 + w * 32 + i * 16 + c16;
      float mx = -1e30f;
#pragma unroll
      for (int j = 0; j < 4; ++j)
#pragma unroll
        for (int r = 0; r < 4; ++r) {
          int key = k0 + j * 16 + q4 * 4 + r;
          float v = st[i][j][r] * SM_SCALE;
          v = (key > qcol) ? -1e30f : v;
          st[i][j][r] = v;
          mx = fmaxf(mx, v);
        }
      mx = fmaxf(mx, __shfl_xor(mx, 16));
      mx = fmaxf(mx, __shfl_xor(mx, 32));
      float mold = m_run[i];
      float mn = fmaxf(mold, mx);
      alpha[i] = __expf(mold - mn);
      m_run[i] = mn;
#pragma unroll
      for (int j = 0; j < 4; ++j)
#pragma unroll
        for (int r = 0; r < 4; ++r)
          st[i][j][r] = __expf(st[i][j][r] - mn);
    }
#pragma unroll
    for (int i = 0; i < 2; ++i) {
#pragma unroll
      for (int j = 0; j < 8; ++j)
#pragma unroll
        for (int r = 0; r < 4; ++r)
          of[i][j][r] *= alpha[i];
#pragma unroll
      for (int r = 0; r < 4; ++r) ofl[i][r] *= alpha[i];
    }
#pragma unroll
    for (int i = 0; i < 2; ++i)
#pragma unroll
      for (int j = 0; j < 4; ++j)
        *(vshort4*)(pw + (i * 16 + c16) * 72 + j * 16 + q4 * 4) =
            pack4(st[i][j][0], st[i][j][1], st[i][j][2], st[i][j][3]);

#pragma unroll
    for (int kk = 0; kk < 2; ++kk) {
      vbf16x8 p0 = ld_frag(pw + (c16) * 72 + kk * 32 + q4 * 8);
      vbf16x8 p1 = ld_frag(pw + (16 + c16) * 72 + kk * 32 + q4 * 8);
#pragma unroll
      for (int jd = 0; jd < 8; ++jd) {
        vbf16x8 vf = ld_frag(kvV + (jd * 16 + c16) * 72 + kk * 32 + q4 * 8);
        of[0][jd] = mfma16(vf, p0, of[0][jd]);
        of[1][jd] = mfma16(vf, p1, of[1][jd]);
      }
      ofl[0] = mfma16(onesf, p0, ofl[0]);
      ofl[1] = mfma16(onesf, p1, ofl[1]);
    }
  }

#pragma unroll
  for (int i = 0; i < 2; ++i) {
    int lr = w * 32 + i * 16 + c16;
    int qrow = q0 + lr;
    float l = ofl[i][0];
    if (chunk < 0) {
      float inv_l = 1.f / l;
#pragma unroll
      for (int jd = 0; jd < 8; ++jd)
        *(vshort4*)(attnb + (size_t)qrow * QSZ + h * HD + jd * 16 + q4 * 4) =
            pack4(of[i][jd][0] * inv_l, of[i][jd][1] * inv_l,
                  of[i][jd][2] * inv_l, of[i][jd][3] * inv_l);
    } else if (chunk == 0) {
#pragma unroll
      for (int jd = 0; jd < 8; ++jd)
        *(vshort4*)(attnb + (size_t)qrow * QSZ + h * HD + jd * 16 + q4 * 4) =
            pack4(of[i][jd][0], of[i][jd][1], of[i][jd][2], of[i][jd][3]);
      if (q4 == 0) { ml[t * 512 + lr * 4 + 0] = m_run[i]; ml[t * 512 + lr * 4 + 1] = l; }
    } else {
#pragma unroll
      for (int jd = 0; jd < 8; ++jd)
        *(vshort4*)(part1 + (size_t)t * 16384 + lr * 128 + jd * 16 + q4 * 4) =
            pack4(of[i][jd][0], of[i][jd][1], of[i][jd][2], of[i][jd][3]);
      if (q4 == 0) { ml[t * 512 + lr * 4 + 2] = m_run[i]; ml[t * 512 + lr * 4 + 3] = l; }
    }
  }
}

// ---------------------------------------------------------------------------
__global__ __launch_bounds__(256) void combine_kernel(
    unsigned short* __restrict__ attnb, const unsigned short* __restrict__ part1,
    const float* __restrict__ ml)
{
  int t = blockIdx.x;
  int h = t >> 3, qt = (t & 7) + 8;
  int lr = threadIdx.x >> 1, ch = (threadIdx.x & 1) * 64;
  int row = qt * 128 + lr;
  float m0 = ml[t * 512 + lr * 4 + 0], l0 = ml[t * 512 + lr * 4 + 1];
  float m1 = ml[t * 512 + lr * 4 + 2], l1 = ml[t * 512 + lr * 4 + 3];
  float M = fmaxf(m0, m1);
  float w0 = __expf(m0 - M), w1 = __expf(m1 - M);
  float inv = 1.f / (l0 * w0 + l1 * w1);
  unsigned short* dst = attnb + (size_t)row * QSZ + h * HD + ch;
  const unsigned short* src = part1 + (size_t)t * 16384 + lr * 128 + ch;
#pragma unroll
  for (int k = 0; k < 8; ++k) {
    vshort8 a = *(const vshort8*)(dst + k * 8);
    vshort8 b = *(const vshort8*)(src + k * 8);
    vshort8 o;
#pragma unroll
    for (int jj = 0; jj < 8; ++jj)
      o[jj] = (short)f2bf((bf2f((unsigned short)a[jj]) * w0 +
                           bf2f((unsigned short)b[jj]) * w1) * inv);
    *(vshort8*)(dst + k * 8) = o;
  }
}

// ---------------------------------------------------------------------------
extern "C" void kernel_launch(void* const* d_in, const int* in_sizes, int n_in,
                              void* d_out, int out_size, void* d_ws, size_t ws_size,
                              hipStream_t stream)
{
  const void* hidden = d_in[0];
  const int*  pos    = (const int*)d_in[1];
  const int*  qkv_qw = (const int*)d_in[2];
  const int*  qkv_qz = (const int*)d_in[3];
  const void* qkv_sc = d_in[4];
  const void* qkv_bs = d_in[5];
  const int*  o_qw   = (const int*)d_in[6];
  const int*  o_qz   = (const int*)d_in[7];
  const void* o_sc   = d_in[8];

  char* ws = (char*)d_ws;
  unsigned short* hidbf = (unsigned short*)d_out;  // dead once gemm1 done

  if (ws_size >= 67052560ULL) {
    // ------- big layout: single-launch GEMMs -------
    unsigned short* qkvb   = (unsigned short*)ws;               // [2048][4608]
    unsigned short* attnb  = (unsigned short*)(ws + 18874368);  // [2048][3584]
    unsigned short* W      = (unsigned short*)(ws + 33554432);  // weights 33 MB
    unsigned short* part1  = W;                                  // after gemm1
    float*          mlbuf  = (float*)(ws + 33554432 + 7340032);
    unsigned short* scbf1  = (unsigned short*)(ws + 66584576);
    unsigned short* scbf2  = (unsigned short*)(ws + 66842624);
    unsigned short* biasbf = (unsigned short*)(ws + 67043328);
    int*            flag   = (int*)(ws + 67052544);

    detect_dtype<<<1, 256, 0, stream>>>((const unsigned short*)hidden, flag);
    convert_bf8<<<3584, 256, 0, stream>>>(hidden, hidbf, flag);
    convert_bf8<<<63, 256, 0, stream>>>(qkv_sc, scbf1, flag);
    convert_bf<<<18, 256, 0, stream>>>(qkv_bs, biasbf, flag);
    convert_bf8<<<49, 256, 0, stream>>>(o_sc, scbf2, flag);

    dequant_awq<<<2016, 256, 0, stream>>>(qkv_qw, qkv_qz, scbf1, W, 3584, 576, 576, 4608);
    gemm_bt<<<dim3(36, 16), 256, 0, stream>>>(hidbf, W, biasbf, qkvb, 0, 4608, 3584, nullptr);
    rope_kernel<<<16384, 256, 0, stream>>>(qkvb, pos);
    attn_kernel<<<672, 256, 0, stream>>>(qkvb, attnb, part1, mlbuf);
    combine_kernel<<<224, 256, 0, stream>>>(attnb, part1, mlbuf);
    dequant_awq<<<1568, 256, 0, stream>>>(o_qw, o_qz, scbf2, W, 3584, 448, 448, 3584);
    gemm_bt<<<dim3(28, 16), 256, 0, stream>>>(attnb, W, nullptr, d_out, 0, 3584, 3584, flag);
  } else {
    // ------- chunked fallback (known-safe 43.7 MB) -------
    unsigned short* qkvb   = (unsigned short*)ws;               // [2048][4608]
    unsigned short* attnb  = (unsigned short*)(ws + 18874368);  // [2048][3584]
    unsigned short* wscr1  = attnb;                             // [2304][3584]
    unsigned short* part1  = (unsigned short*)(ws + 35389440);  // [224][16384]
    float*          mlbuf  = (float*)(ws + 42729472);           // [224][512]
    int*            flag   = (int*)(ws + 43188224);
    unsigned short* scbf1  = (unsigned short*)(ws + 43188240);
    unsigned short* scbf2  = (unsigned short*)(ws + 43446288);
    unsigned short* biasbf = (unsigned short*)(ws + 43646992);
    unsigned short* wscr2  = qkvb;

    detect_dtype<<<1, 256, 0, stream>>>((const unsigned short*)hidden, flag);
    convert_bf8<<<3584, 256, 0, stream>>>(hidden, hidbf, flag);
    convert_bf8<<<63, 256, 0, stream>>>(qkv_sc, scbf1, flag);
    convert_bf<<<18, 256, 0, stream>>>(qkv_bs, biasbf, flag);
    convert_bf8<<<49, 256, 0, stream>>>(o_sc, scbf2, flag);

    for (int c = 0; c < 2; ++c) {
      dequant_awq<<<1008, 256, 0, stream>>>(
          qkv_qw + c * 288, qkv_qz + c * 288, scbf1 + c * 2304, wscr1,
          3584, 288, 576, 4608);
      gemm_bt<<<dim3(18, 16), 256, 0, stream>>>(
          hidbf, wscr1, biasbf + c * 2304, qkvb, c * 2304, 4608, 3584, nullptr);
    }
    rope_kernel<<<16384, 256, 0, stream>>>(qkvb, pos);
    attn_kernel<<<672, 256, 0, stream>>>(qkvb, attnb, part1, mlbuf);
    combine_kernel<<<224, 256, 0, stream>>>(attnb, part1, mlbuf);
    for (int c = 0; c < 2; ++c) {
      dequant_awq<<<784, 256, 0, stream>>>(
          o_qw + c * 224, o_qz + c * 224, scbf2 + c * 1792, wscr2,
          3584, 224, 448, 3584);
      gemm_bt<<<dim3(14, 16), 256, 0, stream>>>(
          attnb, wscr2, nullptr, d_out, c * 1792, 3584, 3584, flag);
    }
  }
}

// Round 7
// 414.501 us; speedup vs baseline: 1.9381x; 1.0546x over previous
//
#include <hip/hip_runtime.h>
#include <stdint.h>

// ---------------------------------------------------------------------------
// Qwen2-7B attention block on gfx950.
// R7: GEMM K-loop double-buffered with fine-grained s_waitcnt vmcnt(4)
//     (AITER-style; raw asm barriers so the compiler can't force vmcnt(0)).
//     RoPE via precomputed sincos table (131k sincos instead of 4.2M).
// ---------------------------------------------------------------------------

typedef short vshort4 __attribute__((ext_vector_type(4)));
typedef short vshort8 __attribute__((ext_vector_type(8)));
typedef __bf16 vbf16x8 __attribute__((ext_vector_type(8)));
typedef float vfloat4 __attribute__((ext_vector_type(4)));

#define SEQ 2048
#define NH 28
#define KVH 4
#define HD 128
#define QSZ 3584
#define QKV_N 4608
#define SM_SCALE 0.08838834764831845f

__device__ __forceinline__ float bf2f(unsigned short h) {
  union { unsigned int u; float f; } x; x.u = ((unsigned int)h) << 16; return x.f;
}
__device__ __forceinline__ unsigned short f2bf(float f) {
  union { unsigned int u; float f; } x; x.f = f;
  x.u += 0x7fff + ((x.u >> 16) & 1);
  return (unsigned short)(x.u >> 16);
}
__device__ __forceinline__ vbf16x8 ld_frag(const unsigned short* p) {
  return __builtin_bit_cast(vbf16x8, *(const vshort8*)p);
}
__device__ __forceinline__ vfloat4 mfma16(vbf16x8 a, vbf16x8 b, vfloat4 c) {
  return __builtin_amdgcn_mfma_f32_16x16x32_bf16(a, b, c, 0, 0, 0);
}
__device__ __forceinline__ void async_cp16(const unsigned short* g, unsigned short* l) {
  __builtin_amdgcn_global_load_lds((const __attribute__((address_space(1))) void*)g,
                                   (__attribute__((address_space(3))) void*)l, 16, 0, 0);
}
__device__ __forceinline__ vshort4 pack4(float a, float b, float c, float d) {
  vshort4 r; r[0] = (short)f2bf(a); r[1] = (short)f2bf(b);
  r[2] = (short)f2bf(c); r[3] = (short)f2bf(d); return r;
}

// ---------------------------------------------------------------------------
__global__ __launch_bounds__(256) void detect_dtype(
    const unsigned short* __restrict__ h, int* __restrict__ flag)
{
  __shared__ int red[256];
  int cnt = 0;
#pragma unroll
  for (int i = 0; i < 8; ++i) {
    unsigned short u = h[threadIdx.x * 8 + i];
    int e = (u >> 7) & 0xFF;
    cnt += (e >= 100 && e <= 150) ? 1 : 0;
  }
  red[threadIdx.x] = cnt;
  __syncthreads();
  for (int s = 128; s > 0; s >>= 1) {
    if (threadIdx.x < s) red[threadIdx.x] += red[threadIdx.x + s];
    __syncthreads();
  }
  if (threadIdx.x == 0) flag[0] = (red[0] >= 1700) ? 1 : 0;
}

__global__ __launch_bounds__(256) void convert_bf(
    const void* __restrict__ src, unsigned short* __restrict__ dst,
    const int* __restrict__ flag)
{
  int i = blockIdx.x * 256 + threadIdx.x;
  if (flag[0]) dst[i] = ((const unsigned short*)src)[i];
  else         dst[i] = f2bf(((const float*)src)[i]);
}

__global__ __launch_bounds__(256) void convert_bf8(
    const void* __restrict__ src, unsigned short* __restrict__ dst,
    const int* __restrict__ flag)
{
  int i = (blockIdx.x * 256 + threadIdx.x) * 8;
  if (flag[0]) {
    *(vshort8*)(dst + i) = *(const vshort8*)((const unsigned short*)src + i);
  } else {
    const float* s = (const float*)src + i;
    float4 a = *(const float4*)s;
    float4 b = *(const float4*)(s + 4);
    vshort8 o;
    o[0] = (short)f2bf(a.x); o[1] = (short)f2bf(a.y);
    o[2] = (short)f2bf(a.z); o[3] = (short)f2bf(a.w);
    o[4] = (short)f2bf(b.x); o[5] = (short)f2bf(b.y);
    o[6] = (short)f2bf(b.z); o[7] = (short)f2bf(b.w);
    *(vshort8*)(dst + i) = o;
  }
}

// ---------------------------------------------------------------------------
__global__ __launch_bounds__(256) void dequant_awq(
    const int* __restrict__ qw, const int* __restrict__ qz,
    const unsigned short* __restrict__ scales,
    unsigned short* __restrict__ Wt,
    int Kdim, int CwChunk, int CwStride, int NoutStride)
{
  int idx = blockIdx.x * 256 + threadIdx.x;   // total = (Kdim/4)*CwChunk
  int kq = Kdim >> 2;
  int k4 = idx % kq;
  int c  = idx / kq;
  int k  = k4 * 4;
  int g  = k >> 7;
  int w0 = qw[(size_t)(k + 0) * CwStride + c];
  int w1 = qw[(size_t)(k + 1) * CwStride + c];
  int w2 = qw[(size_t)(k + 2) * CwStride + c];
  int w3 = qw[(size_t)(k + 3) * CwStride + c];
  int z  = qz[(size_t)g * CwStride + c];
#pragma unroll
  for (int j = 0; j < 8; ++j) {
    int sh = 4 * j;
    float zn = (float)((z >> sh) & 0xF);
    float s  = bf2f(scales[(size_t)g * NoutStride + c * 8 + j]);
    vshort4 o;
    o[0] = (short)f2bf(((float)((w0 >> sh) & 0xF) - zn) * s);
    o[1] = (short)f2bf(((float)((w1 >> sh) & 0xF) - zn) * s);
    o[2] = (short)f2bf(((float)((w2 >> sh) & 0xF) - zn) * s);
    o[3] = (short)f2bf(((float)((w3 >> sh) & 0xF) - zn) * s);
    *(vshort4*)(Wt + (size_t)(c * 8 + j) * Kdim + k) = o;
  }
}

// ---------------------------------------------------------------------------
// bf16 GEMM, XOR-swizzled LDS, double-buffered staging with vmcnt(4).
// Iter k: issue DMA for k+1 into buf[1-cur]; wait the 4 older loads only;
// barrier; ds_read+MFMA from buf[cur]; lgkmcnt(0)+barrier; swap.
// ---------------------------------------------------------------------------
__global__ __launch_bounds__(256) void gemm_bt(
    const unsigned short* __restrict__ A,
    const unsigned short* __restrict__ Bt,
    const unsigned short* __restrict__ bias,
    void* __restrict__ Cv, int n_base, int ldc, int K,
    const int* __restrict__ oflag)
{
  __shared__ __align__(16) unsigned short As[2 * 128 * 32];
  __shared__ __align__(16) unsigned short Bs[2 * 128 * 32];
  const int tid = threadIdx.x;
  const int w = tid >> 6, lane = tid & 63;
  const int c16 = lane & 15, q4 = lane >> 4;
  const int m0 = blockIdx.y * 128, n0 = blockIdx.x * 128;
  const int wr = (w >> 1) * 64, wc = (w & 1) * 64;

  vfloat4 acc[4][4];
#pragma unroll
  for (int i = 0; i < 4; ++i)
#pragma unroll
    for (int j = 0; j < 4; ++j) { vfloat4 z = {0.f, 0.f, 0.f, 0.f}; acc[i][j] = z; }

  // staging: slot = tid (rows 0-63) / 256+tid (rows 64-127); swizzled source
  const int srow = tid >> 2;
  const int gsub = (tid & 3) ^ ((tid >> 3) & 3);
  const unsigned short* aP0 = A  + (size_t)(m0 + srow) * K + gsub * 8;
  const unsigned short* aP1 = A  + (size_t)(m0 + 64 + srow) * K + gsub * 8;
  const unsigned short* bP0 = Bt + (size_t)(n0 + srow) * K + gsub * 8;
  const unsigned short* bP1 = Bt + (size_t)(n0 + 64 + srow) * K + gsub * 8;
  const int ldsW = w * 512;  // wave-uniform DMA base (elements)

  // loop-invariant swizzled frag-read offsets
  int offA[4], offB[4];
#pragma unroll
  for (int i = 0; i < 4; ++i) {
    int ra = wr + i * 16 + c16;
    offA[i] = ra * 32 + (q4 ^ ((ra >> 1) & 3)) * 8;
    int rb = wc + i * 16 + c16;
    offB[i] = rb * 32 + (q4 ^ ((rb >> 1) & 3)) * 8;
  }

  const int nIter = K >> 5;
  int co = 0, no = 4096;   // current / next buffer element offsets

  // prologue: stage tile 0 into buf0
  async_cp16(aP0, As + co + ldsW);
  async_cp16(aP1, As + co + 2048 + ldsW);
  async_cp16(bP0, Bs + co + ldsW);
  async_cp16(bP1, Bs + co + 2048 + ldsW);
  aP0 += 32; aP1 += 32; bP0 += 32; bP1 += 32;

  for (int k = 0; k < nIter; ++k) {
    if (k + 1 < nIter) {
      async_cp16(aP0, As + no + ldsW);
      async_cp16(aP1, As + no + 2048 + ldsW);
      async_cp16(bP0, Bs + no + ldsW);
      async_cp16(bP1, Bs + no + 2048 + ldsW);
      aP0 += 32; aP1 += 32; bP0 += 32; bP1 += 32;
      asm volatile("s_waitcnt vmcnt(4)" ::: "memory");
    } else {
      asm volatile("s_waitcnt vmcnt(0)" ::: "memory");
    }
    asm volatile("s_barrier" ::: "memory");   // buf[co] visible to all waves
    vbf16x8 af[4], bf[4];
#pragma unroll
    for (int i = 0; i < 4; ++i) af[i] = ld_frag(As + co + offA[i]);
#pragma unroll
    for (int j = 0; j < 4; ++j) bf[j] = ld_frag(Bs + co + offB[j]);
#pragma unroll
    for (int i = 0; i < 4; ++i)
#pragma unroll
      for (int j = 0; j < 4; ++j)
        acc[i][j] = mfma16(af[i], bf[j], acc[i][j]);
    // all this wave's ds_reads fully retired, then release buf[co]
    asm volatile("s_waitcnt lgkmcnt(0)" ::: "memory");
    asm volatile("s_barrier" ::: "memory");
    int t = co; co = no; no = t;
  }

  const int bfm = (oflag == nullptr) ? 1 : oflag[0];
#pragma unroll
  for (int i = 0; i < 4; ++i) {
    int m = m0 + wr + i * 16 + q4 * 4;
#pragma unroll
    for (int j = 0; j < 4; ++j) {
      int n = wc + j * 16 + c16 + n0;
      float bv = bias ? bf2f(bias[n]) : 0.f;
#pragma unroll
      for (int r = 0; r < 4; ++r) {
        float v = acc[i][j][r] + bv;
        size_t idx = (size_t)(m + r) * ldc + n + n_base;
        if (bfm) ((unsigned short*)Cv)[idx] = f2bf(v);
        else     ((float*)Cv)[idx] = v;
      }
    }
  }
}

// ---------------------------------------------------------------------------
// RoPE: precompute sincos table [SEQ][64] (float2), then vectorized apply.
// ---------------------------------------------------------------------------
__global__ __launch_bounds__(256) void rope_table(
    const int* __restrict__ pos, float2* __restrict__ tbl)
{
  int idx = blockIdx.x * 256 + threadIdx.x;  // SEQ*64 = 131072
  int j = idx & 63, s = idx >> 6;
  float inv = exp2f(-(float)j * 0.31143079014569017f);  // 1e6^(-j/64)
  float ang = (float)pos[s] * inv;
  float sn, cs;
  sincosf(ang, &sn, &cs);
  tbl[idx] = make_float2(cs, sn);
}

__global__ __launch_bounds__(256) void rope_apply(
    unsigned short* __restrict__ qkv, const float2* __restrict__ tbl)
{
  int idx = blockIdx.x * 256 + threadIdx.x;  // SEQ*32*16 = 1048576
  int j4 = idx & 15;
  int h2 = (idx >> 4) & 31;
  int s = idx >> 9;
  int jb = j4 * 4;
  unsigned short* row = qkv + (size_t)s * QKV_N
                        + ((h2 < NH) ? h2 * HD : QSZ + (h2 - NH) * HD);
  vshort4 x1 = *(const vshort4*)(row + jb);
  vshort4 x2 = *(const vshort4*)(row + jb + 64);
  const float2* tp = tbl + s * 64 + jb;
  vshort4 o1, o2;
#pragma unroll
  for (int q = 0; q < 4; ++q) {
    float2 cn = tp[q];
    float a = bf2f((unsigned short)x1[q]);
    float b = bf2f((unsigned short)x2[q]);
    o1[q] = (short)f2bf(a * cn.x - b * cn.y);
    o2[q] = (short)f2bf(b * cn.x + a * cn.y);
  }
  *(vshort4*)(row + jb) = o1;
  *(vshort4*)(row + jb + 64) = o2;
}

// ---------------------------------------------------------------------------
// GQA causal flash attention, transposed formulation (unchanged from R6).
// ---------------------------------------------------------------------------
__global__ __launch_bounds__(256, 2) void attn_kernel(
    const unsigned short* __restrict__ qkv,
    unsigned short* __restrict__ attnb,
    unsigned short* __restrict__ part1,
    float* __restrict__ ml)
{
  __shared__ __align__(16) unsigned short kvK[64 * 136];
  __shared__ __align__(16) unsigned short kvV[128 * 72];
  __shared__ __align__(16) unsigned short pb[4 * 32 * 72];
  const int tid = threadIdx.x, w = tid >> 6, lane = tid & 63;
  const int c16 = lane & 15, q4 = lane >> 4;

  int bid = blockIdx.x;
  int h, qt, chunk, kt0, kt1, t = 0;
  if (bid < 448) {
    h = bid >> 4; int s = bid & 15;
    qt = 15 - (s >> 1); chunk = s & 1;
    int half = qt + 1;
    kt0 = chunk * half; kt1 = kt0 + half;
    t = h * 8 + (qt - 8);
  } else {
    int d = bid - 448; h = d >> 3; qt = 7 - (d & 7); chunk = -1;
    kt0 = 0; kt1 = 2 * (qt + 1);
  }
  const int q0 = qt * 128;
  const int kvh = h / 7;
  unsigned short* pw = pb + w * 2304;

  vbf16x8 qf[2][4];
#pragma unroll
  for (int i = 0; i < 2; ++i)
#pragma unroll
    for (int kk = 0; kk < 4; ++kk)
      qf[i][kk] = ld_frag(qkv + (size_t)(q0 + w * 32 + i * 16 + c16) * QKV_N
                          + h * HD + kk * 32 + q4 * 8);

  vfloat4 of[2][8];
  vfloat4 ofl[2];
  float m_run[2];
#pragma unroll
  for (int i = 0; i < 2; ++i) {
    m_run[i] = -1e30f;
    vfloat4 z = {0.f, 0.f, 0.f, 0.f};
    ofl[i] = z;
#pragma unroll
    for (int j = 0; j < 8; ++j) of[i][j] = z;
  }
  const vshort8 ones_s = {(short)0x3F80, (short)0x3F80, (short)0x3F80, (short)0x3F80,
                          (short)0x3F80, (short)0x3F80, (short)0x3F80, (short)0x3F80};
  const vbf16x8 onesf = __builtin_bit_cast(vbf16x8, ones_s);

  vshort8 kreg[4], vreg[4];
#pragma unroll
  for (int it = 0; it < 4; ++it) {
    int ch = it * 256 + tid;
    kreg[it] = *(const vshort8*)(qkv + (size_t)(kt0 * 64 + (ch >> 4)) * QKV_N
                                 + QSZ + kvh * HD + (ch & 15) * 8);
    vreg[it] = *(const vshort8*)(qkv + (size_t)(kt0 * 64 + lane) * QKV_N
                                 + QSZ + 512 + kvh * HD + (it * 4 + w) * 8);
  }

  for (int kt = kt0; kt < kt1; ++kt) {
    const int k0 = kt * 64;
    __syncthreads();
#pragma unroll
    for (int it = 0; it < 4; ++it) {
      int ch = it * 256 + tid;
      *(vshort8*)(kvK + (ch >> 4) * 136 + (ch & 15) * 8) = kreg[it];
    }
#pragma unroll
    for (int it = 0; it < 4; ++it) {
      int sub = it * 4 + w;
#pragma unroll
      for (int jj = 0; jj < 8; ++jj)
        kvV[(sub * 8 + jj) * 72 + lane] = (unsigned short)vreg[it][jj];
    }
    __syncthreads();
    if (kt + 1 < kt1) {
#pragma unroll
      for (int it = 0; it < 4; ++it) {
        int ch = it * 256 + tid;
        kreg[it] = *(const vshort8*)(qkv + (size_t)((kt + 1) * 64 + (ch >> 4)) * QKV_N
                                     + QSZ + kvh * HD + (ch & 15) * 8);
        vreg[it] = *(const vshort8*)(qkv + (size_t)((kt + 1) * 64 + lane) * QKV_N
                                     + QSZ + 512 + kvh * HD + (it * 4 + w) * 8);
      }
    }

    vfloat4 st[2][4];
#pragma unroll
    for (int i = 0; i < 2; ++i)
#pragma unroll
      for (int j = 0; j < 4; ++j) { vfloat4 z = {0.f, 0.f, 0.f, 0.f}; st[i][j] = z; }
#pragma unroll
    for (int j = 0; j < 4; ++j)
#pragma unroll
      for (int kk = 0; kk < 4; ++kk) {
        vbf16x8 kf = ld_frag(kvK + (j * 16 + c16) * 136 + kk * 32 + q4 * 8);
        st[0][j] = mfma16(kf, qf[0][kk], st[0][j]);
        st[1][j] = mfma16(kf, qf[1][kk], st[1][j]);
      }

    float alpha[2];
#pragma unroll
    for (int i = 0; i < 2; ++i) {
      const int qcol = q0 + w * 32 + i * 16 + c16;
      float mx = -1e30f;
#pragma unroll
      for (int j = 0; j < 4; ++j)
#pragma unroll
        for (int r = 0; r < 4; ++r) {
          int key = k0 + j * 16 + q4 * 4 + r;
          float v = st[i][j][r] * SM_SCALE;
          v = (key > qcol) ? -1e30f : v;
          st[i][j][r] = v;
          mx = fmaxf(mx, v);
        }
      mx = fmaxf(mx, __shfl_xor(mx, 16));
      mx = fmaxf(mx, __shfl_xor(mx, 32));
      float mold = m_run[i];
      float mn = fmaxf(mold, mx);
      alpha[i] = __expf(mold - mn);
      m_run[i] = mn;
#pragma unroll
      for (int j = 0; j < 4; ++j)
#pragma unroll
        for (int r = 0; r < 4; ++r)
          st[i][j][r] = __expf(st[i][j][r] - mn);
    }
#pragma unroll
    for (int i = 0; i < 2; ++i) {
#pragma unroll
      for (int j = 0; j < 8; ++j)
#pragma unroll
        for (int r = 0; r < 4; ++r)
          of[i][j][r] *= alpha[i];
#pragma unroll
      for (int r = 0; r < 4; ++r) ofl[i][r] *= alpha[i];
    }
#pragma unroll
    for (int i = 0; i < 2; ++i)
#pragma unroll
      for (int j = 0; j < 4; ++j)
        *(vshort4*)(pw + (i * 16 + c16) * 72 + j * 16 + q4 * 4) =
            pack4(st[i][j][0], st[i][j][1], st[i][j][2], st[i][j][3]);

#pragma unroll
    for (int kk = 0; kk < 2; ++kk) {
      vbf16x8 p0 = ld_frag(pw + (c16) * 72 + kk * 32 + q4 * 8);
      vbf16x8 p1 = ld_frag(pw + (16 + c16) * 72 + kk * 32 + q4 * 8);
#pragma unroll
      for (int jd = 0; jd < 8; ++jd) {
        vbf16x8 vf = ld_frag(kvV + (jd * 16 + c16) * 72 + kk * 32 + q4 * 8);
        of[0][jd] = mfma16(vf, p0, of[0][jd]);
        of[1][jd] = mfma16(vf, p1, of[1][jd]);
      }
      ofl[0] = mfma16(onesf, p0, ofl[0]);
      ofl[1] = mfma16(onesf, p1, ofl[1]);
    }
  }

#pragma unroll
  for (int i = 0; i < 2; ++i) {
    int lr = w * 32 + i * 16 + c16;
    int qrow = q0 + lr;
    float l = ofl[i][0];
    if (chunk < 0) {
      float inv_l = 1.f / l;
#pragma unroll
      for (int jd = 0; jd < 8; ++jd)
        *(vshort4*)(attnb + (size_t)qrow * QSZ + h * HD + jd * 16 + q4 * 4) =
            pack4(of[i][jd][0] * inv_l, of[i][jd][1] * inv_l,
                  of[i][jd][2] * inv_l, of[i][jd][3] * inv_l);
    } else if (chunk == 0) {
#pragma unroll
      for (int jd = 0; jd < 8; ++jd)
        *(vshort4*)(attnb + (size_t)qrow * QSZ + h * HD + jd * 16 + q4 * 4) =
            pack4(of[i][jd][0], of[i][jd][1], of[i][jd][2], of[i][jd][3]);
      if (q4 == 0) { ml[t * 512 + lr * 4 + 0] = m_run[i]; ml[t * 512 + lr * 4 + 1] = l; }
    } else {
#pragma unroll
      for (int jd = 0; jd < 8; ++jd)
        *(vshort4*)(part1 + (size_t)t * 16384 + lr * 128 + jd * 16 + q4 * 4) =
            pack4(of[i][jd][0], of[i][jd][1], of[i][jd][2], of[i][jd][3]);
      if (q4 == 0) { ml[t * 512 + lr * 4 + 2] = m_run[i]; ml[t * 512 + lr * 4 + 3] = l; }
    }
  }
}

// ---------------------------------------------------------------------------
__global__ __launch_bounds__(256) void combine_kernel(
    unsigned short* __restrict__ attnb, const unsigned short* __restrict__ part1,
    const float* __restrict__ ml)
{
  int t = blockIdx.x;
  int h = t >> 3, qt = (t & 7) + 8;
  int lr = threadIdx.x >> 1, ch = (threadIdx.x & 1) * 64;
  int row = qt * 128 + lr;
  float m0 = ml[t * 512 + lr * 4 + 0], l0 = ml[t * 512 + lr * 4 + 1];
  float m1 = ml[t * 512 + lr * 4 + 2], l1 = ml[t * 512 + lr * 4 + 3];
  float M = fmaxf(m0, m1);
  float w0 = __expf(m0 - M), w1 = __expf(m1 - M);
  float inv = 1.f / (l0 * w0 + l1 * w1);
  unsigned short* dst = attnb + (size_t)row * QSZ + h * HD + ch;
  const unsigned short* src = part1 + (size_t)t * 16384 + lr * 128 + ch;
#pragma unroll
  for (int k = 0; k < 8; ++k) {
    vshort8 a = *(const vshort8*)(dst + k * 8);
    vshort8 b = *(const vshort8*)(src + k * 8);
    vshort8 o;
#pragma unroll
    for (int jj = 0; jj < 8; ++jj)
      o[jj] = (short)f2bf((bf2f((unsigned short)a[jj]) * w0 +
                           bf2f((unsigned short)b[jj]) * w1) * inv);
    *(vshort8*)(dst + k * 8) = o;
  }
}

// ---------------------------------------------------------------------------
extern "C" void kernel_launch(void* const* d_in, const int* in_sizes, int n_in,
                              void* d_out, int out_size, void* d_ws, size_t ws_size,
                              hipStream_t stream)
{
  const void* hidden = d_in[0];
  const int*  pos    = (const int*)d_in[1];
  const int*  qkv_qw = (const int*)d_in[2];
  const int*  qkv_qz = (const int*)d_in[3];
  const void* qkv_sc = d_in[4];
  const void* qkv_bs = d_in[5];
  const int*  o_qw   = (const int*)d_in[6];
  const int*  o_qz   = (const int*)d_in[7];
  const void* o_sc   = d_in[8];

  char* ws = (char*)d_ws;
  unsigned short* hidbf = (unsigned short*)d_out;  // dead once gemm1 done

  if (ws_size >= 67052560ULL) {
    // ------- big layout: single-launch GEMMs -------
    unsigned short* qkvb   = (unsigned short*)ws;               // [2048][4608]
    unsigned short* attnb  = (unsigned short*)(ws + 18874368);  // [2048][3584]
    unsigned short* W      = (unsigned short*)(ws + 33554432);  // weights 33 MB
    unsigned short* part1  = W;                                  // after gemm1
    float*          mlbuf  = (float*)(ws + 33554432 + 7340032);
    float2*         tbl    = (float2*)(ws + 41943040);           // 1 MB, rope only
    unsigned short* scbf1  = (unsigned short*)(ws + 66584576);
    unsigned short* scbf2  = (unsigned short*)(ws + 66842624);
    unsigned short* biasbf = (unsigned short*)(ws + 67043328);
    int*            flag   = (int*)(ws + 67052544);

    detect_dtype<<<1, 256, 0, stream>>>((const unsigned short*)hidden, flag);
    convert_bf8<<<3584, 256, 0, stream>>>(hidden, hidbf, flag);
    convert_bf8<<<63, 256, 0, stream>>>(qkv_sc, scbf1, flag);
    convert_bf<<<18, 256, 0, stream>>>(qkv_bs, biasbf, flag);
    convert_bf8<<<49, 256, 0, stream>>>(o_sc, scbf2, flag);

    dequant_awq<<<2016, 256, 0, stream>>>(qkv_qw, qkv_qz, scbf1, W, 3584, 576, 576, 4608);
    gemm_bt<<<dim3(36, 16), 256, 0, stream>>>(hidbf, W, biasbf, qkvb, 0, 4608, 3584, nullptr);
    rope_table<<<512, 256, 0, stream>>>(pos, tbl);
    rope_apply<<<4096, 256, 0, stream>>>(qkvb, tbl);
    attn_kernel<<<672, 256, 0, stream>>>(qkvb, attnb, part1, mlbuf);
    combine_kernel<<<224, 256, 0, stream>>>(attnb, part1, mlbuf);
    dequant_awq<<<1568, 256, 0, stream>>>(o_qw, o_qz, scbf2, W, 3584, 448, 448, 3584);
    gemm_bt<<<dim3(28, 16), 256, 0, stream>>>(attnb, W, nullptr, d_out, 0, 3584, 3584, flag);
  } else {
    // ------- chunked fallback (known-safe 43.7 MB) -------
    unsigned short* qkvb   = (unsigned short*)ws;               // [2048][4608]
    unsigned short* attnb  = (unsigned short*)(ws + 18874368);  // [2048][3584]
    unsigned short* wscr1  = attnb;                             // [2304][3584]
    float2*         tbl    = (float2*)(ws + 18874368);          // rope only
    unsigned short* part1  = (unsigned short*)(ws + 35389440);  // [224][16384]
    float*          mlbuf  = (float*)(ws + 42729472);           // [224][512]
    int*            flag   = (int*)(ws + 43188224);
    unsigned short* scbf1  = (unsigned short*)(ws + 43188240);
    unsigned short* scbf2  = (unsigned short*)(ws + 43446288);
    unsigned short* biasbf = (unsigned short*)(ws + 43646992);
    unsigned short* wscr2  = qkvb;

    detect_dtype<<<1, 256, 0, stream>>>((const unsigned short*)hidden, flag);
    convert_bf8<<<3584, 256, 0, stream>>>(hidden, hidbf, flag);
    convert_bf8<<<63, 256, 0, stream>>>(qkv_sc, scbf1, flag);
    convert_bf<<<18, 256, 0, stream>>>(qkv_bs, biasbf, flag);
    convert_bf8<<<49, 256, 0, stream>>>(o_sc, scbf2, flag);

    for (int c = 0; c < 2; ++c) {
      dequant_awq<<<1008, 256, 0, stream>>>(
          qkv_qw + c * 288, qkv_qz + c * 288, scbf1 + c * 2304, wscr1,
          3584, 288, 576, 4608);
      gemm_bt<<<dim3(18, 16), 256, 0, stream>>>(
          hidbf, wscr1, biasbf + c * 2304, qkvb, c * 2304, 4608, 3584, nullptr);
    }
    rope_table<<<512, 256, 0, stream>>>(pos, tbl);
    rope_apply<<<4096, 256, 0, stream>>>(qkvb, tbl);
    attn_kernel<<<672, 256, 0, stream>>>(qkvb, attnb, part1, mlbuf);
    combine_kernel<<<224, 256, 0, stream>>>(attnb, part1, mlbuf);
    for (int c = 0; c < 2; ++c) {
      dequant_awq<<<784, 256, 0, stream>>>(
          o_qw + c * 224, o_qz + c * 224, scbf2 + c * 1792, wscr2,
          3584, 224, 448, 3584);
      gemm_bt<<<dim3(14, 16), 256, 0, stream>>>(
          attnb, wscr2, nullptr, d_out, c * 1792, 3584, 3584, flag);
    }
  }
}